// Round 3
// baseline (1151.389 us; speedup 1.0000x reference)
//
#include <hip/hip_runtime.h>

#define CDIM 64
#define COARSE_SHIFT 10          // 1024 rows per coarse bucket
#define CHUNK 8192
#define MAXB 256                 // >= max coarse buckets (200000>>10 = 196)

// ---------------- init: residual slots of d_out (+ optional concat buffer) ----------------
__global__ void init_kernel(const float4* __restrict__ user_emb,
                            const float4* __restrict__ ent_emb,
                            float4* __restrict__ outUserRes,
                            float4* __restrict__ outNodeRes,
                            float4* __restrict__ allA,      // may be null (compact path)
                            long nuC4, long neC4) {
    long i = (long)blockIdx.x * blockDim.x + threadIdx.x;
    if (i < nuC4) {
        float4 v = user_emb[i];
        outUserRes[i] = v; outNodeRes[i] = v;
        if (allA) allA[i] = v;
    }
    if (i < neC4) {
        float4 v = ent_emb[i];
        outNodeRes[nuC4 + i] = v;
        if (allA) allA[nuC4 + i] = v;
    }
}

// ---------------- coarse histogram (LDS-staged) ----------------
__global__ void hist_coarse(const int* __restrict__ dst, int n,
                            int* __restrict__ cnt, int Bc) {
    __shared__ int h[MAXB];
    for (int i = threadIdx.x; i < MAXB; i += blockDim.x) h[i] = 0;
    __syncthreads();
    int stride = gridDim.x * blockDim.x;
    for (int e = blockIdx.x * blockDim.x + threadIdx.x; e < n; e += stride)
        atomicAdd(&h[dst[e] >> COARSE_SHIFT], 1);
    __syncthreads();
    for (int b = threadIdx.x; b < Bc; b += blockDim.x)
        if (h[b]) atomicAdd(&cnt[b], h[b]);
}

// ---------------- small exclusive scan (single WG, n<=256) ----------------
__global__ void scan_small(const int* __restrict__ cnt, int* __restrict__ start,
                           int* __restrict__ cursor, int n) {
    __shared__ int tmp[256];
    int x = threadIdx.x;
    int v = (x < n) ? cnt[x] : 0;
    tmp[x] = v; __syncthreads();
    for (int off = 1; off < 256; off <<= 1) {
        int t = (x >= off) ? tmp[x - off] : 0;
        __syncthreads();
        tmp[x] += t;
        __syncthreads();
    }
    if (x < n) { start[x] = tmp[x] - v; cursor[x] = tmp[x] - v; }
    if (x == n - 1) start[n] = tmp[x];
}

// ---------------- coarse binning, LDS-staged segment writes ----------------
// key = rowlocal<<22 | typ<<18 | src   (rowlocal<1024, typ<16, src<2^18)
__global__ void bin_pairs(const int* __restrict__ dst, const int* __restrict__ src,
                          const int* __restrict__ typ, int typeBias, int n,
                          int* __restrict__ cursor, int* __restrict__ stage) {
    __shared__ int h[MAXB];
    __shared__ int base[MAXB];
    int cs = blockIdx.x * CHUNK;
    int ce = min(cs + CHUNK, n);
    for (int i = threadIdx.x; i < MAXB; i += blockDim.x) h[i] = 0;
    __syncthreads();
    for (int e = cs + threadIdx.x; e < ce; e += blockDim.x)
        atomicAdd(&h[dst[e] >> COARSE_SHIFT], 1);
    __syncthreads();
    for (int b = threadIdx.x; b < MAXB; b += blockDim.x) {
        int c = h[b];
        base[b] = c ? atomicAdd(&cursor[b], c) : 0;
        h[b] = 0;
    }
    __syncthreads();
    for (int e = cs + threadIdx.x; e < ce; e += blockDim.x) {
        int d = dst[e];
        int b = d >> COARSE_SHIFT;
        int off = atomicAdd(&h[b], 1);
        stage[base[b] + off] = ((d & 1023) << 22) | ((typ[e] + typeBias) << 18) | src[e];
    }
}

// user variant: key = rowlocal<<22 | col (col<2^22), parallel val array
__global__ void bin_user(const int* __restrict__ row, const int* __restrict__ col,
                         const float* __restrict__ val, int n,
                         int* __restrict__ cursor,
                         int* __restrict__ stage, float* __restrict__ stageVal) {
    __shared__ int h[MAXB];
    __shared__ int base[MAXB];
    int cs = blockIdx.x * CHUNK;
    int ce = min(cs + CHUNK, n);
    for (int i = threadIdx.x; i < MAXB; i += blockDim.x) h[i] = 0;
    __syncthreads();
    for (int e = cs + threadIdx.x; e < ce; e += blockDim.x)
        atomicAdd(&h[row[e] >> COARSE_SHIFT], 1);
    __syncthreads();
    for (int b = threadIdx.x; b < MAXB; b += blockDim.x) {
        int c = h[b];
        base[b] = c ? atomicAdd(&cursor[b], c) : 0;
        h[b] = 0;
    }
    __syncthreads();
    for (int e = cs + threadIdx.x; e < ce; e += blockDim.x) {
        int d = row[e];
        int b = d >> COARSE_SHIFT;
        int off = atomicAdd(&h[b], 1);
        int pos = base[b] + off;
        stage[pos] = ((d & 1023) << 22) | col[e];
        stageVal[pos] = val[e];
    }
}

// ---------------- full per-row sort within coarse bucket (L2-resident) ----------------
__global__ void __launch_bounds__(256)
subsort(const int* __restrict__ coarseStart,
        const int* __restrict__ stage, const float* __restrict__ stageVal,
        int* __restrict__ bin, float* __restrict__ binVal,
        int* __restrict__ rowStart, int Bc, int N, int total) {
    __shared__ int h[1024];
    __shared__ int base[1024];
    __shared__ int sarr[256];
    int c = blockIdx.x;
    int s = coarseStart[c], e = coarseStart[c + 1];
    for (int i = threadIdx.x; i < 1024; i += 256) h[i] = 0;
    __syncthreads();
    for (int j = s + threadIdx.x; j < e; j += 256)
        atomicAdd(&h[(stage[j] >> 22) & 1023], 1);
    __syncthreads();
    int t = threadIdx.x;
    int l0 = h[4*t], l1 = h[4*t+1], l2 = h[4*t+2], l3 = h[4*t+3];
    int lsum = l0 + l1 + l2 + l3;
    sarr[t] = lsum;
    __syncthreads();
    for (int off = 1; off < 256; off <<= 1) {
        int v = (t >= off) ? sarr[t - off] : 0;
        __syncthreads();
        sarr[t] += v;
        __syncthreads();
    }
    int excl = sarr[t] - lsum;
    base[4*t] = excl; base[4*t+1] = excl + l0;
    base[4*t+2] = excl + l0 + l1; base[4*t+3] = excl + l0 + l1 + l2;
    __syncthreads();
    int rowBase = c << COARSE_SHIFT;
    for (int i = threadIdx.x; i < 1024; i += 256) {
        int gr = rowBase + i;
        if (gr < N) rowStart[gr] = s + base[i];
    }
    if (threadIdx.x == 0 && c == Bc - 1) rowStart[N] = total;
    for (int i = threadIdx.x; i < 1024; i += 256) h[i] = 0;
    __syncthreads();
    for (int j = s + threadIdx.x; j < e; j += 256) {
        int k = stage[j];
        int r = (k >> 22) & 1023;
        int pos = s + base[r] + atomicAdd(&h[r], 1);
        bin[pos] = k;
        if (binVal) binVal[pos] = stageVal[j];
    }
}

// ---------------- gathers ----------------
// One wave per dest row. lane = 16*q + l: q = edge slot base, l = float4 group.
// Keys for the whole row loaded once, coalesced; distributed by __shfl.
// CORRECTNESS INVARIANT: every __shfl executes in wave-uniform control flow
// (all 64 lanes active). Loop trip count nb = ceil(cap/16) is wave-uniform.
// Tail slots (e >= cap) are neutralized by indexing a ZERO ROW in the LDS
// weight tile (1 cndmask) so all 4 gathers per iteration issue unconditionally
// and stay in flight together. Lanes >= deg hold myk = 0 (valid row 0).

__device__ __forceinline__ void fma4(float4& acc, const float4 v, const float4 w) {
    acc.x += v.x * w.x; acc.y += v.y * w.y;
    acc.z += v.z * w.z; acc.w += v.w * w.w;
}

__global__ void __launch_bounds__(256)
ent_gather(const float* __restrict__ entCur,
           const float4* __restrict__ weight,
           const int* __restrict__ rowStart,
           const int* __restrict__ bin,
           float* __restrict__ entNew,
           float* __restrict__ entNorm,
           int NE) {
    __shared__ float4 wlds[16 * 16];                 // row 15 = zeros (mask row)
    for (int i = threadIdx.x; i < 15 * 16; i += blockDim.x) wlds[i] = weight[i];
    for (int i = threadIdx.x; i < 16; i += blockDim.x)
        wlds[15 * 16 + i] = make_float4(0.f, 0.f, 0.f, 0.f);
    __syncthreads();
    int row = blockIdx.x * (blockDim.x >> 6) + (threadIdx.x >> 6);
    int lane = threadIdx.x & 63;
    int q = lane >> 4, l = lane & 15;
    if (row >= NE) return;
    int start = rowStart[row], end = rowStart[row + 1];
    int deg = end - start;
    int myk = (lane < deg) ? bin[start + lane] : 0;  // one coalesced 64-wide load
    int cap = deg < 64 ? deg : 64;
    int nb = (cap + 15) >> 4;                        // uniform trip count
    float4 acc = make_float4(0.f, 0.f, 0.f, 0.f);
    for (int t = 0; t < nb; ++t) {
        int e0 = (t << 4) + q;                       // e0..e0+12 all <= 63
        int k0 = __shfl(myk, e0,      64);
        int k1 = __shfl(myk, e0 + 4,  64);
        int k2 = __shfl(myk, e0 + 8,  64);
        int k3 = __shfl(myk, e0 + 12, 64);
        float4 v0 = ((const float4*)(entCur + (long)(k0 & 0x3FFFF) * CDIM))[l];
        float4 v1 = ((const float4*)(entCur + (long)(k1 & 0x3FFFF) * CDIM))[l];
        float4 v2 = ((const float4*)(entCur + (long)(k2 & 0x3FFFF) * CDIM))[l];
        float4 v3 = ((const float4*)(entCur + (long)(k3 & 0x3FFFF) * CDIM))[l];
        int r0 = (e0      < cap) ? ((k0 >> 18) & 15) : 15;
        int r1 = (e0 + 4  < cap) ? ((k1 >> 18) & 15) : 15;
        int r2 = (e0 + 8  < cap) ? ((k2 >> 18) & 15) : 15;
        int r3 = (e0 + 12 < cap) ? ((k3 >> 18) & 15) : 15;
        fma4(acc, v0, wlds[r0 * 16 + l]);
        fma4(acc, v1, wlds[r1 * 16 + l]);
        fma4(acc, v2, wlds[r2 * 16 + l]);
        fma4(acc, v3, wlds[r3 * 16 + l]);
    }
    for (int j = start + 64 + q; j < end; j += 4) {  // rare overflow (deg > 64)
        int k = bin[j];
        float4 v = ((const float4*)(entCur + (long)(k & 0x3FFFF) * CDIM))[l];
        fma4(acc, v, wlds[((k >> 18) & 15) * 16 + l]);
    }
    #pragma unroll
    for (int off = 16; off < 64; off <<= 1) {
        acc.x += __shfl_xor(acc.x, off, 64);
        acc.y += __shfl_xor(acc.y, off, 64);
        acc.z += __shfl_xor(acc.z, off, 64);
        acc.w += __shfl_xor(acc.w, off, 64);
    }
    float inv = 1.0f / fmaxf((float)deg, 1.0f);
    float4 mean = make_float4(acc.x * inv, acc.y * inv, acc.z * inv, acc.w * inv);
    float q2 = mean.x * mean.x + mean.y * mean.y + mean.z * mean.z + mean.w * mean.w;
    #pragma unroll
    for (int off = 1; off < 16; off <<= 1) q2 += __shfl_xor(q2, off, 64);
    float n = fmaxf(sqrtf(q2), 1e-12f);
    float rn = 1.0f / n;
    if (q == 0) {
        ((float4*)(entNew + (long)row * CDIM))[l] =
            make_float4(mean.x * rn, mean.y * rn, mean.z * rn, mean.w * rn);
        if (l == 0) entNorm[row] = n;
    }
}

// UNI=true: baseAll is the contiguous [NN][64] hop buffer (no per-edge select).
// UNI=false: baseAll = user part, entCur = entity part (round-2 semantics).
template<bool UNI>
__global__ void __launch_bounds__(256)
node_gather_t(const float* __restrict__ baseAll,
              const float* __restrict__ entCur,
              const float4* __restrict__ extraW,
              const int* __restrict__ rowStart,
              const int* __restrict__ bin,
              float* __restrict__ nodeUnew,
              float* __restrict__ resOut,
              int NN, int NU) {
    __shared__ float4 wlds[17 * 16];                 // row 16 = zeros (mask row)
    for (int i = threadIdx.x; i < 16 * 16; i += blockDim.x) wlds[i] = extraW[i];
    for (int i = threadIdx.x; i < 16; i += blockDim.x)
        wlds[16 * 16 + i] = make_float4(0.f, 0.f, 0.f, 0.f);
    __syncthreads();
    int row = blockIdx.x * (blockDim.x >> 6) + (threadIdx.x >> 6);
    int lane = threadIdx.x & 63;
    int q = lane >> 4, l = lane & 15;
    if (row >= NN) return;
    int start = rowStart[row], end = rowStart[row + 1];
    int deg = end - start;
    int myk = (lane < deg) ? bin[start + lane] : 0;
    int cap = deg < 64 ? deg : 64;
    int nb = (cap + 15) >> 4;
    float4 acc = make_float4(0.f, 0.f, 0.f, 0.f);
    for (int t = 0; t < nb; ++t) {
        int e0 = (t << 4) + q;
        int k0 = __shfl(myk, e0,      64);
        int k1 = __shfl(myk, e0 + 4,  64);
        int k2 = __shfl(myk, e0 + 8,  64);
        int k3 = __shfl(myk, e0 + 12, 64);
        int s0 = k0 & 0x3FFFF, s1 = k1 & 0x3FFFF;
        int s2 = k2 & 0x3FFFF, s3 = k3 & 0x3FFFF;
        const float *b0, *b1, *b2, *b3;
        if (UNI) {
            b0 = baseAll + (long)s0 * CDIM; b1 = baseAll + (long)s1 * CDIM;
            b2 = baseAll + (long)s2 * CDIM; b3 = baseAll + (long)s3 * CDIM;
        } else {
            b0 = (s0 < NU) ? baseAll + (long)s0 * CDIM : entCur + (long)(s0 - NU) * CDIM;
            b1 = (s1 < NU) ? baseAll + (long)s1 * CDIM : entCur + (long)(s1 - NU) * CDIM;
            b2 = (s2 < NU) ? baseAll + (long)s2 * CDIM : entCur + (long)(s2 - NU) * CDIM;
            b3 = (s3 < NU) ? baseAll + (long)s3 * CDIM : entCur + (long)(s3 - NU) * CDIM;
        }
        float4 v0 = ((const float4*)b0)[l];
        float4 v1 = ((const float4*)b1)[l];
        float4 v2 = ((const float4*)b2)[l];
        float4 v3 = ((const float4*)b3)[l];
        int r0 = (e0      < cap) ? ((k0 >> 18) & 15) : 16;
        int r1 = (e0 + 4  < cap) ? ((k1 >> 18) & 15) : 16;
        int r2 = (e0 + 8  < cap) ? ((k2 >> 18) & 15) : 16;
        int r3 = (e0 + 12 < cap) ? ((k3 >> 18) & 15) : 16;
        fma4(acc, v0, wlds[r0 * 16 + l]);
        fma4(acc, v1, wlds[r1 * 16 + l]);
        fma4(acc, v2, wlds[r2 * 16 + l]);
        fma4(acc, v3, wlds[r3 * 16 + l]);
    }
    for (int j = start + 64 + q; j < end; j += 4) {
        int k = bin[j];
        int s = k & 0x3FFFF;
        const float* b;
        if (UNI) b = baseAll + (long)s * CDIM;
        else b = (s < NU) ? baseAll + (long)s * CDIM : entCur + (long)(s - NU) * CDIM;
        float4 v = ((const float4*)b)[l];
        fma4(acc, v, wlds[((k >> 18) & 15) * 16 + l]);
    }
    #pragma unroll
    for (int off = 16; off < 64; off <<= 1) {
        acc.x += __shfl_xor(acc.x, off, 64);
        acc.y += __shfl_xor(acc.y, off, 64);
        acc.z += __shfl_xor(acc.z, off, 64);
        acc.w += __shfl_xor(acc.w, off, 64);
    }
    float inv = 1.0f / fmaxf((float)deg, 1.0f);
    float4 mean = make_float4(acc.x * inv, acc.y * inv, acc.z * inv, acc.w * inv);
    float q2 = mean.x * mean.x + mean.y * mean.y + mean.z * mean.z + mean.w * mean.w;
    #pragma unroll
    for (int off = 1; off < 16; off <<= 1) q2 += __shfl_xor(q2, off, 64);
    float rn = 1.0f / fmaxf(sqrtf(q2), 1e-12f);
    if (q == 0) {
        float4 o = make_float4(mean.x * rn, mean.y * rn, mean.z * rn, mean.w * rn);
        float4* resRow = (float4*)(resOut + (long)row * CDIM);
        float4 rv = resRow[l];
        resRow[l] = make_float4(rv.x + o.x, rv.y + o.y, rv.z + o.z, rv.w + o.w);
        if (row < NU) ((float4*)(nodeUnew + (long)row * CDIM))[l] = o;
    }
}

__global__ void __launch_bounds__(256)
user_gather(const float* __restrict__ entNew,
            const float* __restrict__ entNorm,
            const int* __restrict__ rowStart,
            const int* __restrict__ bin,
            const float* __restrict__ binVal,
            float* __restrict__ userRes,
            int NU) {
    int row = blockIdx.x * (blockDim.x >> 6) + (threadIdx.x >> 6);
    int lane = threadIdx.x & 63;
    int q = lane >> 4, l = lane & 15;
    if (row >= NU) return;
    int start = rowStart[row], end = rowStart[row + 1];
    int deg = end - start;
    int myk = 0; float myv = 0.f;
    if (lane < deg) { myk = bin[start + lane]; myv = binVal[start + lane]; }
    int cap = deg < 64 ? deg : 64;
    int nb = (cap + 15) >> 4;
    float4 acc = make_float4(0.f, 0.f, 0.f, 0.f);
    for (int t = 0; t < nb; ++t) {
        int e0 = (t << 4) + q;
        int k0 = __shfl(myk, e0,      64);
        int k1 = __shfl(myk, e0 + 4,  64);
        int k2 = __shfl(myk, e0 + 8,  64);
        int k3 = __shfl(myk, e0 + 12, 64);
        float a0 = __shfl(myv, e0,      64);
        float a1 = __shfl(myv, e0 + 4,  64);
        float a2 = __shfl(myv, e0 + 8,  64);
        float a3 = __shfl(myv, e0 + 12, 64);
        int c0 = k0 & 0x3FFFFF, c1 = k1 & 0x3FFFFF;
        int c2 = k2 & 0x3FFFFF, c3 = k3 & 0x3FFFFF;
        float f0 = (e0      < cap) ? entNorm[c0] * a0 : 0.f;
        float f1 = (e0 + 4  < cap) ? entNorm[c1] * a1 : 0.f;
        float f2 = (e0 + 8  < cap) ? entNorm[c2] * a2 : 0.f;
        float f3 = (e0 + 12 < cap) ? entNorm[c3] * a3 : 0.f;
        float4 v0 = ((const float4*)(entNew + (long)c0 * CDIM))[l];
        float4 v1 = ((const float4*)(entNew + (long)c1 * CDIM))[l];
        float4 v2 = ((const float4*)(entNew + (long)c2 * CDIM))[l];
        float4 v3 = ((const float4*)(entNew + (long)c3 * CDIM))[l];
        acc.x += v0.x * f0; acc.y += v0.y * f0; acc.z += v0.z * f0; acc.w += v0.w * f0;
        acc.x += v1.x * f1; acc.y += v1.y * f1; acc.z += v1.z * f1; acc.w += v1.w * f1;
        acc.x += v2.x * f2; acc.y += v2.y * f2; acc.z += v2.z * f2; acc.w += v2.w * f2;
        acc.x += v3.x * f3; acc.y += v3.y * f3; acc.z += v3.z * f3; acc.w += v3.w * f3;
    }
    for (int j = start + 64 + q; j < end; j += 4) {
        int col = bin[j] & 0x3FFFFF;
        float f = entNorm[col] * binVal[j];
        float4 v = ((const float4*)(entNew + (long)col * CDIM))[l];
        acc.x += v.x * f; acc.y += v.y * f;
        acc.z += v.z * f; acc.w += v.w * f;
    }
    #pragma unroll
    for (int off = 16; off < 64; off <<= 1) {
        acc.x += __shfl_xor(acc.x, off, 64);
        acc.y += __shfl_xor(acc.y, off, 64);
        acc.z += __shfl_xor(acc.z, off, 64);
        acc.w += __shfl_xor(acc.w, off, 64);
    }
    float q2 = acc.x * acc.x + acc.y * acc.y + acc.z * acc.z + acc.w * acc.w;
    #pragma unroll
    for (int off = 1; off < 16; off <<= 1) q2 += __shfl_xor(q2, off, 64);
    float rn = 1.0f / fmaxf(sqrtf(q2), 1e-12f);
    if (q == 0) {
        float4* resRow = (float4*)(userRes + (long)row * CDIM);
        float4 rv = resRow[l];
        resRow[l] = make_float4(rv.x + acc.x * rn, rv.y + acc.y * rn,
                                rv.z + acc.z * rn, rv.w + acc.w * rn);
    }
}

__global__ void fill_debug(float* __restrict__ out, long n, float val) {
    long i = (long)blockIdx.x * blockDim.x + threadIdx.x;
    if (i < n) out[i] = val;
}

extern "C" void kernel_launch(void* const* d_in, const int* in_sizes, int n_in,
                              void* d_out, int out_size, void* d_ws, size_t ws_size,
                              hipStream_t stream) {
    const float* user_emb = (const float*)d_in[0];
    const float* ent_emb  = (const float*)d_in[1];
    const float* weight   = (const float*)d_in[2];
    const float* extraW   = (const float*)d_in[3];
    const float* imVal    = (const float*)d_in[4];
    const int*   eidx     = (const int*)d_in[5];
    const int*   etype    = (const int*)d_in[6];
    const int*   xidx     = (const int*)d_in[7];
    const int*   xtype    = (const int*)d_in[8];
    const int*   imRow    = (const int*)d_in[9];
    const int*   imCol    = (const int*)d_in[10];

    const int NU  = in_sizes[0] / CDIM;
    const int NE  = in_sizes[1] / CDIM;
    const int NN  = NU + NE;
    const int E   = in_sizes[5] / 2;
    const int E2  = in_sizes[7] / 2;
    const int NNZ = in_sizes[4];
    const long nuC = (long)NU * CDIM, neC = (long)NE * CDIM, nnC = (long)NN * CDIM;

    const int BcE = (NE + 1023) >> 10, BcN = (NN + 1023) >> 10, BcU = (NU + 1023) >> 10;

    float* out = (float*)d_out;
    float* outUserRes = out;            // [0 : nuC]
    float* entOut     = out + nuC;      // [nuC : nnC] final-hop entity output
    float* outNodeRes = out + nnC;      // [nnC : 2nnC]

    // ---- workspace layout ----
    size_t commonBytes = (size_t)NE * 4                    // entNorm
                       + (size_t)(E + E2 + NNZ) * 4 * 2    // stage + bin keys
                       + (size_t)NNZ * 4 * 2               // stageVal + binVal
                       + (size_t)(3 * MAXB) * 4            // coarse counts
                       + (size_t)(3 * (MAXB + 1)) * 4      // coarse starts
                       + (size_t)(3 * MAXB) * 4            // cursors
                       + (size_t)(NE + NN + NU + 3) * 4;   // rowStart CSR arrays
    size_t reqCompact = commonBytes + (size_t)(neC + 2 * nuC) * 4;
    size_t reqUni     = commonBytes + (size_t)(2 * nnC) * 4;
    if (ws_size < reqCompact) {
        long total = 2 * nnC;
        fill_debug<<<(total + 255) / 256, 256, 0, stream>>>(out, total, (float)(ws_size >> 20));
        return;
    }
    const bool uni = (ws_size >= reqUni);

    char* w = (char*)d_ws;
    float* entNorm  = (float*)w; w += (size_t)NE * 4;
    int* stageEnt   = (int*)w;   w += (size_t)E * 4;
    int* stageNode  = (int*)w;   w += (size_t)E2 * 4;
    int* stageU     = (int*)w;   w += (size_t)NNZ * 4;
    float* stageUv  = (float*)w; w += (size_t)NNZ * 4;
    int* binEnt     = (int*)w;   w += (size_t)E * 4;
    int* binNode    = (int*)w;   w += (size_t)E2 * 4;
    int* binU       = (int*)w;   w += (size_t)NNZ * 4;
    float* binUv    = (float*)w; w += (size_t)NNZ * 4;
    int* cntC       = (int*)w;   w += (size_t)(3 * MAXB) * 4;
    int* startE     = (int*)w;   w += (size_t)(MAXB + 1) * 4;
    int* startN     = (int*)w;   w += (size_t)(MAXB + 1) * 4;
    int* startU     = (int*)w;   w += (size_t)(MAXB + 1) * 4;
    int* curE       = (int*)w;   w += (size_t)MAXB * 4;
    int* curN       = (int*)w;   w += (size_t)MAXB * 4;
    int* curU       = (int*)w;   w += (size_t)MAXB * 4;
    int* rowSE      = (int*)w;   w += (size_t)(NE + 1) * 4;
    int* rowSN      = (int*)w;   w += (size_t)(NN + 1) * 4;
    int* rowSU      = (int*)w;   w += (size_t)(NU + 1) * 4;

    float* allA = nullptr, *allB = nullptr;              // unified path
    float* entA = nullptr, *nodeU_A = nullptr, *nodeU_B = nullptr;  // compact path
    if (uni) {
        allA = (float*)w; w += (size_t)nnC * 4;
        allB = (float*)w; w += (size_t)nnC * 4;
    } else {
        entA    = (float*)w; w += (size_t)neC * 4;
        nodeU_A = (float*)w; w += (size_t)nuC * 4;
        nodeU_B = (float*)w; w += (size_t)nuC * 4;
    }

    const int* head = eidx;  const int* tail = eidx + E;
    const int* eh   = xidx;  const int* et   = xidx + E2;

    hipMemsetAsync(cntC, 0, (size_t)(3 * MAXB) * 4, stream);

    long initN4 = (nuC > neC ? nuC : neC) / 4;
    init_kernel<<<(initN4 + 255) / 256, 256, 0, stream>>>(
        (const float4*)user_emb, (const float4*)ent_emb,
        (float4*)outUserRes, (float4*)outNodeRes,
        (float4*)allA, nuC / 4, neC / 4);

    // ---- build: hist -> scan -> coarse bin -> per-row subsort (CSR) ----
    hist_coarse<<<256, 256, 0, stream>>>(head,  E,   cntC,            BcE);
    hist_coarse<<<256, 256, 0, stream>>>(eh,    E2,  cntC + MAXB,     BcN);
    hist_coarse<<<256, 256, 0, stream>>>(imRow, NNZ, cntC + 2 * MAXB, BcU);

    scan_small<<<1, 256, 0, stream>>>(cntC,            startE, curE, BcE);
    scan_small<<<1, 256, 0, stream>>>(cntC + MAXB,     startN, curN, BcN);
    scan_small<<<1, 256, 0, stream>>>(cntC + 2 * MAXB, startU, curU, BcU);

    bin_pairs<<<(E  + CHUNK - 1) / CHUNK, 256, 0, stream>>>(head, tail, etype, -1, E,  curE, stageEnt);
    bin_pairs<<<(E2 + CHUNK - 1) / CHUNK, 256, 0, stream>>>(eh,   et,   xtype,  0, E2, curN, stageNode);
    bin_user <<<(NNZ + CHUNK - 1) / CHUNK, 256, 0, stream>>>(imRow, imCol, imVal, NNZ, curU, stageU, stageUv);

    subsort<<<BcE, 256, 0, stream>>>(startE, stageEnt,  nullptr, binEnt,  nullptr, rowSE, BcE, NE, E);
    subsort<<<BcN, 256, 0, stream>>>(startN, stageNode, nullptr, binNode, nullptr, rowSN, BcN, NN, E2);
    subsort<<<BcU, 256, 0, stream>>>(startU, stageU,    stageUv, binU,    binUv,   rowSU, BcU, NU, NNZ);

    // ---- 3 hops ----
    if (uni) {
        // hop h: read allCur (contiguous [NN][64]); ent writes entity half of the
        // other buffer; node writes user half of the other buffer.
        const float* allCurH[3]  = { allA, allB, allA };
        float*       entNewH[3]  = { allB + (size_t)NU * CDIM, allA + (size_t)NU * CDIM, entOut };
        float*       nodeNewH[3] = { allB, allA, allB /*scratch*/ };
        for (int hop = 0; hop < 3; ++hop) {
            ent_gather<<<(NE + 3) / 4, 256, 0, stream>>>(
                allCurH[hop] + (size_t)NU * CDIM, (const float4*)weight,
                rowSE, binEnt, entNewH[hop], entNorm, NE);
            node_gather_t<true><<<(NN + 3) / 4, 256, 0, stream>>>(
                allCurH[hop], nullptr, (const float4*)extraW, rowSN, binNode,
                nodeNewH[hop], outNodeRes, NN, NU);
            user_gather<<<(NU + 3) / 4, 256, 0, stream>>>(
                entNewH[hop], entNorm, rowSU, binU, binUv, outUserRes, NU);
        }
    } else {
        const float* entCurP  = ent_emb;   float* entNewP  = entOut;
        const float* nodeOldP = user_emb;  float* nodeNewP = nodeU_A;
        for (int hop = 0; hop < 3; ++hop) {
            ent_gather<<<(NE + 3) / 4, 256, 0, stream>>>(
                entCurP, (const float4*)weight, rowSE, binEnt, entNewP, entNorm, NE);
            node_gather_t<false><<<(NN + 3) / 4, 256, 0, stream>>>(
                nodeOldP, entCurP, (const float4*)extraW, rowSN, binNode,
                nodeNewP, outNodeRes, NN, NU);
            user_gather<<<(NU + 3) / 4, 256, 0, stream>>>(
                entNewP, entNorm, rowSU, binU, binUv, outUserRes, NU);
            if (hop == 0) {
                entCurP = entOut;  entNewP = entA;
                nodeOldP = nodeU_A; nodeNewP = nodeU_B;
            } else if (hop == 1) {
                entCurP = entA;    entNewP = entOut;
                nodeOldP = nodeU_B; nodeNewP = nodeU_A;
            }
        }
    }
}

// Round 4
// 1028.461 us; speedup vs baseline: 1.1195x; 1.1195x over previous
//
#include <hip/hip_runtime.h>

#define CDIM 64
#define COARSE_SHIFT 10          // 1024 rows per coarse bucket
#define CHUNK 8192
#define MAXB 256                 // >= max coarse buckets (200000>>10 = 196)

// ---------------- init: residual slots of d_out ----------------
__global__ void init_kernel(const float4* __restrict__ user_emb,
                            const float4* __restrict__ ent_emb,
                            float4* __restrict__ outUserRes,
                            float4* __restrict__ outNodeRes,
                            long nuC4, long neC4) {
    long i = (long)blockIdx.x * blockDim.x + threadIdx.x;
    if (i < nuC4) { float4 v = user_emb[i]; outUserRes[i] = v; outNodeRes[i] = v; }
    if (i < neC4) { outNodeRes[nuC4 + i] = ent_emb[i]; }
}

// ---------------- coarse histogram (LDS-staged) ----------------
__global__ void hist_coarse(const int* __restrict__ dst, int n,
                            int* __restrict__ cnt, int Bc) {
    __shared__ int h[MAXB];
    for (int i = threadIdx.x; i < MAXB; i += blockDim.x) h[i] = 0;
    __syncthreads();
    int stride = gridDim.x * blockDim.x;
    for (int e = blockIdx.x * blockDim.x + threadIdx.x; e < n; e += stride)
        atomicAdd(&h[dst[e] >> COARSE_SHIFT], 1);
    __syncthreads();
    for (int b = threadIdx.x; b < Bc; b += blockDim.x)
        if (h[b]) atomicAdd(&cnt[b], h[b]);
}

// ---------------- small exclusive scan (single WG, n<=256) ----------------
__global__ void scan_small(const int* __restrict__ cnt, int* __restrict__ start,
                           int* __restrict__ cursor, int n) {
    __shared__ int tmp[256];
    int x = threadIdx.x;
    int v = (x < n) ? cnt[x] : 0;
    tmp[x] = v; __syncthreads();
    for (int off = 1; off < 256; off <<= 1) {
        int t = (x >= off) ? tmp[x - off] : 0;
        __syncthreads();
        tmp[x] += t;
        __syncthreads();
    }
    if (x < n) { start[x] = tmp[x] - v; cursor[x] = tmp[x] - v; }
    if (x == n - 1) start[n] = tmp[x];
}

// ---------------- coarse binning, LDS-staged segment writes ----------------
// key = rowlocal<<22 | typ<<18 | src   (rowlocal<1024, typ<16, src<2^18)
__global__ void bin_pairs(const int* __restrict__ dst, const int* __restrict__ src,
                          const int* __restrict__ typ, int typeBias, int n,
                          int* __restrict__ cursor, int* __restrict__ stage) {
    __shared__ int h[MAXB];
    __shared__ int base[MAXB];
    int cs = blockIdx.x * CHUNK;
    int ce = min(cs + CHUNK, n);
    for (int i = threadIdx.x; i < MAXB; i += blockDim.x) h[i] = 0;
    __syncthreads();
    for (int e = cs + threadIdx.x; e < ce; e += blockDim.x)
        atomicAdd(&h[dst[e] >> COARSE_SHIFT], 1);
    __syncthreads();
    for (int b = threadIdx.x; b < MAXB; b += blockDim.x) {
        int c = h[b];
        base[b] = c ? atomicAdd(&cursor[b], c) : 0;
        h[b] = 0;
    }
    __syncthreads();
    for (int e = cs + threadIdx.x; e < ce; e += blockDim.x) {
        int d = dst[e];
        int b = d >> COARSE_SHIFT;
        int off = atomicAdd(&h[b], 1);
        stage[base[b] + off] = ((d & 1023) << 22) | ((typ[e] + typeBias) << 18) | src[e];
    }
}

// user variant: key = rowlocal<<22 | col (col<2^22), parallel val array
__global__ void bin_user(const int* __restrict__ row, const int* __restrict__ col,
                         const float* __restrict__ val, int n,
                         int* __restrict__ cursor,
                         int* __restrict__ stage, float* __restrict__ stageVal) {
    __shared__ int h[MAXB];
    __shared__ int base[MAXB];
    int cs = blockIdx.x * CHUNK;
    int ce = min(cs + CHUNK, n);
    for (int i = threadIdx.x; i < MAXB; i += blockDim.x) h[i] = 0;
    __syncthreads();
    for (int e = cs + threadIdx.x; e < ce; e += blockDim.x)
        atomicAdd(&h[row[e] >> COARSE_SHIFT], 1);
    __syncthreads();
    for (int b = threadIdx.x; b < MAXB; b += blockDim.x) {
        int c = h[b];
        base[b] = c ? atomicAdd(&cursor[b], c) : 0;
        h[b] = 0;
    }
    __syncthreads();
    for (int e = cs + threadIdx.x; e < ce; e += blockDim.x) {
        int d = row[e];
        int b = d >> COARSE_SHIFT;
        int off = atomicAdd(&h[b], 1);
        int pos = base[b] + off;
        stage[pos] = ((d & 1023) << 22) | col[e];
        stageVal[pos] = val[e];
    }
}

// ---------------- full per-row sort within coarse bucket (L2-resident) ----------------
__global__ void __launch_bounds__(256)
subsort(const int* __restrict__ coarseStart,
        const int* __restrict__ stage, const float* __restrict__ stageVal,
        int* __restrict__ bin, float* __restrict__ binVal,
        int* __restrict__ rowStart, int Bc, int N, int total) {
    __shared__ int h[1024];
    __shared__ int base[1024];
    __shared__ int sarr[256];
    int c = blockIdx.x;
    int s = coarseStart[c], e = coarseStart[c + 1];
    for (int i = threadIdx.x; i < 1024; i += 256) h[i] = 0;
    __syncthreads();
    for (int j = s + threadIdx.x; j < e; j += 256)
        atomicAdd(&h[(stage[j] >> 22) & 1023], 1);
    __syncthreads();
    int t = threadIdx.x;
    int l0 = h[4*t], l1 = h[4*t+1], l2 = h[4*t+2], l3 = h[4*t+3];
    int lsum = l0 + l1 + l2 + l3;
    sarr[t] = lsum;
    __syncthreads();
    for (int off = 1; off < 256; off <<= 1) {
        int v = (t >= off) ? sarr[t - off] : 0;
        __syncthreads();
        sarr[t] += v;
        __syncthreads();
    }
    int excl = sarr[t] - lsum;
    base[4*t] = excl; base[4*t+1] = excl + l0;
    base[4*t+2] = excl + l0 + l1; base[4*t+3] = excl + l0 + l1 + l2;
    __syncthreads();
    int rowBase = c << COARSE_SHIFT;
    for (int i = threadIdx.x; i < 1024; i += 256) {
        int gr = rowBase + i;
        if (gr < N) rowStart[gr] = s + base[i];
    }
    if (threadIdx.x == 0 && c == Bc - 1) rowStart[N] = total;
    for (int i = threadIdx.x; i < 1024; i += 256) h[i] = 0;
    __syncthreads();
    for (int j = s + threadIdx.x; j < e; j += 256) {
        int k = stage[j];
        int r = (k >> 22) & 1023;
        int pos = s + base[r] + atomicAdd(&h[r], 1);
        bin[pos] = k;
        if (binVal) binVal[pos] = stageVal[j];
    }
}

// ---------------- gathers ----------------
// One wave per dest row. lane = 16*q + l: q = edge slot base, l = float4 group.
// Keys for the whole row loaded once, coalesced; distributed by __shfl.
// CORRECTNESS INVARIANT: every __shfl executes in wave-uniform control flow
// (all 64 lanes active; ds_bpermute from inactive lanes is undefined).
// Structure: full 16-slot batches (all slots < cap, unconditional loads) +
// one uniform-entry epilogue (cap & 15) where 4 shfls issue uniformly and the
// load+FMA is predicated per slot. No dummy loads, 4 gathers in flight.
// Lanes >= deg hold myk = 0 (valid row 0) so unused shfl results are benign.

__device__ __forceinline__ void fma4(float4& acc, const float4 v, const float4 w) {
    acc.x += v.x * w.x; acc.y += v.y * w.y;
    acc.z += v.z * w.z; acc.w += v.w * w.w;
}

__global__ void __launch_bounds__(256)
ent_gather(const float* __restrict__ entCur,
           const float4* __restrict__ weight,
           const int* __restrict__ rowStart,
           const int* __restrict__ bin,
           float* __restrict__ entNew,
           float* __restrict__ entNorm,
           int NE) {
    __shared__ float4 wlds[15 * 16];
    for (int i = threadIdx.x; i < 15 * 16; i += blockDim.x) wlds[i] = weight[i];
    __syncthreads();
    int row = blockIdx.x * (blockDim.x >> 6) + (threadIdx.x >> 6);
    int lane = threadIdx.x & 63;
    int q = lane >> 4, l = lane & 15;
    if (row >= NE) return;
    int start = rowStart[row], end = rowStart[row + 1];
    int deg = end - start;
    int myk = (lane < deg) ? bin[start + lane] : 0;   // one coalesced 64-wide load
    int cap = deg < 64 ? deg : 64;
    int full = cap >> 4;                              // uniform trip count
    float4 acc = make_float4(0.f, 0.f, 0.f, 0.f);
    for (int t = 0; t < full; ++t) {
        int e0 = (t << 4) + q;                        // all 4 slots < cap
        int k0 = __shfl(myk, e0,      64);
        int k1 = __shfl(myk, e0 + 4,  64);
        int k2 = __shfl(myk, e0 + 8,  64);
        int k3 = __shfl(myk, e0 + 12, 64);
        float4 v0 = ((const float4*)(entCur + (long)(k0 & 0x3FFFF) * CDIM))[l];
        float4 v1 = ((const float4*)(entCur + (long)(k1 & 0x3FFFF) * CDIM))[l];
        float4 v2 = ((const float4*)(entCur + (long)(k2 & 0x3FFFF) * CDIM))[l];
        float4 v3 = ((const float4*)(entCur + (long)(k3 & 0x3FFFF) * CDIM))[l];
        fma4(acc, v0, wlds[((k0 >> 18) & 15) * 16 + l]);
        fma4(acc, v1, wlds[((k1 >> 18) & 15) * 16 + l]);
        fma4(acc, v2, wlds[((k2 >> 18) & 15) * 16 + l]);
        fma4(acc, v3, wlds[((k3 >> 18) & 15) * 16 + l]);
    }
    if (cap & 15) {                                   // uniform entry
        int e0 = (full << 4) + q;                     // e0..e0+12 <= 63
        int k0 = __shfl(myk, e0,      64);
        int k1 = __shfl(myk, e0 + 4,  64);
        int k2 = __shfl(myk, e0 + 8,  64);
        int k3 = __shfl(myk, e0 + 12, 64);
        if (e0 < cap) {
            float4 v = ((const float4*)(entCur + (long)(k0 & 0x3FFFF) * CDIM))[l];
            fma4(acc, v, wlds[((k0 >> 18) & 15) * 16 + l]);
        }
        if (e0 + 4 < cap) {
            float4 v = ((const float4*)(entCur + (long)(k1 & 0x3FFFF) * CDIM))[l];
            fma4(acc, v, wlds[((k1 >> 18) & 15) * 16 + l]);
        }
        if (e0 + 8 < cap) {
            float4 v = ((const float4*)(entCur + (long)(k2 & 0x3FFFF) * CDIM))[l];
            fma4(acc, v, wlds[((k2 >> 18) & 15) * 16 + l]);
        }
        if (e0 + 12 < cap) {
            float4 v = ((const float4*)(entCur + (long)(k3 & 0x3FFFF) * CDIM))[l];
            fma4(acc, v, wlds[((k3 >> 18) & 15) * 16 + l]);
        }
    }
    for (int j = start + 64 + q; j < end; j += 4) {   // rare overflow (deg > 64)
        int k = bin[j];
        float4 v = ((const float4*)(entCur + (long)(k & 0x3FFFF) * CDIM))[l];
        fma4(acc, v, wlds[((k >> 18) & 15) * 16 + l]);
    }
    #pragma unroll
    for (int off = 16; off < 64; off <<= 1) {
        acc.x += __shfl_xor(acc.x, off, 64);
        acc.y += __shfl_xor(acc.y, off, 64);
        acc.z += __shfl_xor(acc.z, off, 64);
        acc.w += __shfl_xor(acc.w, off, 64);
    }
    float inv = 1.0f / fmaxf((float)deg, 1.0f);
    float4 mean = make_float4(acc.x * inv, acc.y * inv, acc.z * inv, acc.w * inv);
    float q2 = mean.x * mean.x + mean.y * mean.y + mean.z * mean.z + mean.w * mean.w;
    #pragma unroll
    for (int off = 1; off < 16; off <<= 1) q2 += __shfl_xor(q2, off, 64);
    float n = fmaxf(sqrtf(q2), 1e-12f);
    float rn = 1.0f / n;
    if (q == 0) {
        ((float4*)(entNew + (long)row * CDIM))[l] =
            make_float4(mean.x * rn, mean.y * rn, mean.z * rn, mean.w * rn);
        if (l == 0) entNorm[row] = n;
    }
}

__global__ void __launch_bounds__(256)
node_gather(const float* __restrict__ nodeUold,
            const float* __restrict__ entCur,
            const float4* __restrict__ extraW,
            const int* __restrict__ rowStart,
            const int* __restrict__ bin,
            float* __restrict__ nodeUnew,
            float* __restrict__ resOut,
            int NN, int NU) {
    __shared__ float4 wlds[16 * 16];
    for (int i = threadIdx.x; i < 16 * 16; i += blockDim.x) wlds[i] = extraW[i];
    __syncthreads();
    int row = blockIdx.x * (blockDim.x >> 6) + (threadIdx.x >> 6);
    int lane = threadIdx.x & 63;
    int q = lane >> 4, l = lane & 15;
    if (row >= NN) return;
    int start = rowStart[row], end = rowStart[row + 1];
    int deg = end - start;
    int myk = (lane < deg) ? bin[start + lane] : 0;
    // hoist residual read: overlaps its latency with the gather loop
    float4* resRow = (float4*)(resOut + (long)row * CDIM);
    float4 rv = make_float4(0.f, 0.f, 0.f, 0.f);
    if (q == 0) rv = resRow[l];
    int cap = deg < 64 ? deg : 64;
    int full = cap >> 4;
    float4 acc = make_float4(0.f, 0.f, 0.f, 0.f);
    for (int t = 0; t < full; ++t) {
        int e0 = (t << 4) + q;
        int k0 = __shfl(myk, e0,      64);
        int k1 = __shfl(myk, e0 + 4,  64);
        int k2 = __shfl(myk, e0 + 8,  64);
        int k3 = __shfl(myk, e0 + 12, 64);
        int s0 = k0 & 0x3FFFF, s1 = k1 & 0x3FFFF;
        int s2 = k2 & 0x3FFFF, s3 = k3 & 0x3FFFF;
        const float* b0 = (s0 < NU) ? nodeUold + (long)s0 * CDIM : entCur + (long)(s0 - NU) * CDIM;
        const float* b1 = (s1 < NU) ? nodeUold + (long)s1 * CDIM : entCur + (long)(s1 - NU) * CDIM;
        const float* b2 = (s2 < NU) ? nodeUold + (long)s2 * CDIM : entCur + (long)(s2 - NU) * CDIM;
        const float* b3 = (s3 < NU) ? nodeUold + (long)s3 * CDIM : entCur + (long)(s3 - NU) * CDIM;
        float4 v0 = ((const float4*)b0)[l];
        float4 v1 = ((const float4*)b1)[l];
        float4 v2 = ((const float4*)b2)[l];
        float4 v3 = ((const float4*)b3)[l];
        fma4(acc, v0, wlds[((k0 >> 18) & 15) * 16 + l]);
        fma4(acc, v1, wlds[((k1 >> 18) & 15) * 16 + l]);
        fma4(acc, v2, wlds[((k2 >> 18) & 15) * 16 + l]);
        fma4(acc, v3, wlds[((k3 >> 18) & 15) * 16 + l]);
    }
    if (cap & 15) {
        int e0 = (full << 4) + q;
        int k0 = __shfl(myk, e0,      64);
        int k1 = __shfl(myk, e0 + 4,  64);
        int k2 = __shfl(myk, e0 + 8,  64);
        int k3 = __shfl(myk, e0 + 12, 64);
        if (e0 < cap) {
            int s = k0 & 0x3FFFF;
            const float* b = (s < NU) ? nodeUold + (long)s * CDIM : entCur + (long)(s - NU) * CDIM;
            fma4(acc, ((const float4*)b)[l], wlds[((k0 >> 18) & 15) * 16 + l]);
        }
        if (e0 + 4 < cap) {
            int s = k1 & 0x3FFFF;
            const float* b = (s < NU) ? nodeUold + (long)s * CDIM : entCur + (long)(s - NU) * CDIM;
            fma4(acc, ((const float4*)b)[l], wlds[((k1 >> 18) & 15) * 16 + l]);
        }
        if (e0 + 8 < cap) {
            int s = k2 & 0x3FFFF;
            const float* b = (s < NU) ? nodeUold + (long)s * CDIM : entCur + (long)(s - NU) * CDIM;
            fma4(acc, ((const float4*)b)[l], wlds[((k2 >> 18) & 15) * 16 + l]);
        }
        if (e0 + 12 < cap) {
            int s = k3 & 0x3FFFF;
            const float* b = (s < NU) ? nodeUold + (long)s * CDIM : entCur + (long)(s - NU) * CDIM;
            fma4(acc, ((const float4*)b)[l], wlds[((k3 >> 18) & 15) * 16 + l]);
        }
    }
    for (int j = start + 64 + q; j < end; j += 4) {
        int k = bin[j];
        int s = k & 0x3FFFF;
        const float* b = (s < NU) ? nodeUold + (long)s * CDIM : entCur + (long)(s - NU) * CDIM;
        float4 v = ((const float4*)b)[l];
        fma4(acc, v, wlds[((k >> 18) & 15) * 16 + l]);
    }
    #pragma unroll
    for (int off = 16; off < 64; off <<= 1) {
        acc.x += __shfl_xor(acc.x, off, 64);
        acc.y += __shfl_xor(acc.y, off, 64);
        acc.z += __shfl_xor(acc.z, off, 64);
        acc.w += __shfl_xor(acc.w, off, 64);
    }
    float inv = 1.0f / fmaxf((float)deg, 1.0f);
    float4 mean = make_float4(acc.x * inv, acc.y * inv, acc.z * inv, acc.w * inv);
    float q2 = mean.x * mean.x + mean.y * mean.y + mean.z * mean.z + mean.w * mean.w;
    #pragma unroll
    for (int off = 1; off < 16; off <<= 1) q2 += __shfl_xor(q2, off, 64);
    float rn = 1.0f / fmaxf(sqrtf(q2), 1e-12f);
    if (q == 0) {
        float4 o = make_float4(mean.x * rn, mean.y * rn, mean.z * rn, mean.w * rn);
        resRow[l] = make_float4(rv.x + o.x, rv.y + o.y, rv.z + o.z, rv.w + o.w);
        if (row < NU) ((float4*)(nodeUnew + (long)row * CDIM))[l] = o;
    }
}

__global__ void __launch_bounds__(256)
user_gather(const float* __restrict__ entNew,
            const float* __restrict__ entNorm,
            const int* __restrict__ rowStart,
            const int* __restrict__ bin,
            const float* __restrict__ binVal,
            float* __restrict__ userRes,
            int NU) {
    int row = blockIdx.x * (blockDim.x >> 6) + (threadIdx.x >> 6);
    int lane = threadIdx.x & 63;
    int q = lane >> 4, l = lane & 15;
    if (row >= NU) return;
    int start = rowStart[row], end = rowStart[row + 1];
    int deg = end - start;
    int myk = 0; float myv = 0.f;
    if (lane < deg) { myk = bin[start + lane]; myv = binVal[start + lane]; }
    float4* resRow = (float4*)(userRes + (long)row * CDIM);
    float4 rv = make_float4(0.f, 0.f, 0.f, 0.f);
    if (q == 0) rv = resRow[l];
    int cap = deg < 64 ? deg : 64;
    int full = cap >> 4;
    float4 acc = make_float4(0.f, 0.f, 0.f, 0.f);
    for (int t = 0; t < full; ++t) {
        int e0 = (t << 4) + q;
        int k0 = __shfl(myk, e0,      64);
        int k1 = __shfl(myk, e0 + 4,  64);
        int k2 = __shfl(myk, e0 + 8,  64);
        int k3 = __shfl(myk, e0 + 12, 64);
        float a0 = __shfl(myv, e0,      64);
        float a1 = __shfl(myv, e0 + 4,  64);
        float a2 = __shfl(myv, e0 + 8,  64);
        float a3 = __shfl(myv, e0 + 12, 64);
        int c0 = k0 & 0x3FFFFF, c1 = k1 & 0x3FFFFF;
        int c2 = k2 & 0x3FFFFF, c3 = k3 & 0x3FFFFF;
        float f0 = entNorm[c0] * a0;
        float f1 = entNorm[c1] * a1;
        float f2 = entNorm[c2] * a2;
        float f3 = entNorm[c3] * a3;
        float4 v0 = ((const float4*)(entNew + (long)c0 * CDIM))[l];
        float4 v1 = ((const float4*)(entNew + (long)c1 * CDIM))[l];
        float4 v2 = ((const float4*)(entNew + (long)c2 * CDIM))[l];
        float4 v3 = ((const float4*)(entNew + (long)c3 * CDIM))[l];
        acc.x += v0.x * f0; acc.y += v0.y * f0; acc.z += v0.z * f0; acc.w += v0.w * f0;
        acc.x += v1.x * f1; acc.y += v1.y * f1; acc.z += v1.z * f1; acc.w += v1.w * f1;
        acc.x += v2.x * f2; acc.y += v2.y * f2; acc.z += v2.z * f2; acc.w += v2.w * f2;
        acc.x += v3.x * f3; acc.y += v3.y * f3; acc.z += v3.z * f3; acc.w += v3.w * f3;
    }
    if (cap & 15) {
        int e0 = (full << 4) + q;
        int k0 = __shfl(myk, e0,      64);
        int k1 = __shfl(myk, e0 + 4,  64);
        int k2 = __shfl(myk, e0 + 8,  64);
        int k3 = __shfl(myk, e0 + 12, 64);
        float a0 = __shfl(myv, e0,      64);
        float a1 = __shfl(myv, e0 + 4,  64);
        float a2 = __shfl(myv, e0 + 8,  64);
        float a3 = __shfl(myv, e0 + 12, 64);
        if (e0 < cap) {
            int c = k0 & 0x3FFFFF; float f = entNorm[c] * a0;
            float4 v = ((const float4*)(entNew + (long)c * CDIM))[l];
            acc.x += v.x * f; acc.y += v.y * f; acc.z += v.z * f; acc.w += v.w * f;
        }
        if (e0 + 4 < cap) {
            int c = k1 & 0x3FFFFF; float f = entNorm[c] * a1;
            float4 v = ((const float4*)(entNew + (long)c * CDIM))[l];
            acc.x += v.x * f; acc.y += v.y * f; acc.z += v.z * f; acc.w += v.w * f;
        }
        if (e0 + 8 < cap) {
            int c = k2 & 0x3FFFFF; float f = entNorm[c] * a2;
            float4 v = ((const float4*)(entNew + (long)c * CDIM))[l];
            acc.x += v.x * f; acc.y += v.y * f; acc.z += v.z * f; acc.w += v.w * f;
        }
        if (e0 + 12 < cap) {
            int c = k3 & 0x3FFFFF; float f = entNorm[c] * a3;
            float4 v = ((const float4*)(entNew + (long)c * CDIM))[l];
            acc.x += v.x * f; acc.y += v.y * f; acc.z += v.z * f; acc.w += v.w * f;
        }
    }
    for (int j = start + 64 + q; j < end; j += 4) {
        int col = bin[j] & 0x3FFFFF;
        float f = entNorm[col] * binVal[j];
        float4 v = ((const float4*)(entNew + (long)col * CDIM))[l];
        acc.x += v.x * f; acc.y += v.y * f;
        acc.z += v.z * f; acc.w += v.w * f;
    }
    #pragma unroll
    for (int off = 16; off < 64; off <<= 1) {
        acc.x += __shfl_xor(acc.x, off, 64);
        acc.y += __shfl_xor(acc.y, off, 64);
        acc.z += __shfl_xor(acc.z, off, 64);
        acc.w += __shfl_xor(acc.w, off, 64);
    }
    float q2 = acc.x * acc.x + acc.y * acc.y + acc.z * acc.z + acc.w * acc.w;
    #pragma unroll
    for (int off = 1; off < 16; off <<= 1) q2 += __shfl_xor(q2, off, 64);
    float rn = 1.0f / fmaxf(sqrtf(q2), 1e-12f);
    if (q == 0) {
        resRow[l] = make_float4(rv.x + acc.x * rn, rv.y + acc.y * rn,
                                rv.z + acc.z * rn, rv.w + acc.w * rn);
    }
}

__global__ void fill_debug(float* __restrict__ out, long n, float val) {
    long i = (long)blockIdx.x * blockDim.x + threadIdx.x;
    if (i < n) out[i] = val;
}

extern "C" void kernel_launch(void* const* d_in, const int* in_sizes, int n_in,
                              void* d_out, int out_size, void* d_ws, size_t ws_size,
                              hipStream_t stream) {
    const float* user_emb = (const float*)d_in[0];
    const float* ent_emb  = (const float*)d_in[1];
    const float* weight   = (const float*)d_in[2];
    const float* extraW   = (const float*)d_in[3];
    const float* imVal    = (const float*)d_in[4];
    const int*   eidx     = (const int*)d_in[5];
    const int*   etype    = (const int*)d_in[6];
    const int*   xidx     = (const int*)d_in[7];
    const int*   xtype    = (const int*)d_in[8];
    const int*   imRow    = (const int*)d_in[9];
    const int*   imCol    = (const int*)d_in[10];

    const int NU  = in_sizes[0] / CDIM;
    const int NE  = in_sizes[1] / CDIM;
    const int NN  = NU + NE;
    const int E   = in_sizes[5] / 2;
    const int E2  = in_sizes[7] / 2;
    const int NNZ = in_sizes[4];
    const long nuC = (long)NU * CDIM, neC = (long)NE * CDIM, nnC = (long)NN * CDIM;

    const int BcE = (NE + 1023) >> 10, BcN = (NN + 1023) >> 10, BcU = (NU + 1023) >> 10;

    float* out = (float*)d_out;
    float* outUserRes = out;            // [0 : nuC]
    float* entOut     = out + nuC;      // [nuC : nnC] ping-pong; final hop lands here
    float* outNodeRes = out + nnC;      // [nnC : 2nnC]

    // ---- workspace layout ----
    size_t required = (size_t)(neC + 2 * nuC) * 4          // entA, nodeU_A, nodeU_B
                    + (size_t)NE * 4                        // entNorm
                    + (size_t)(E + E2 + NNZ) * 4 * 2        // stage + bin keys
                    + (size_t)NNZ * 4 * 2                   // stageVal + binVal
                    + (size_t)(3 * MAXB) * 4                // coarse counts
                    + (size_t)(3 * (MAXB + 1)) * 4          // coarse starts
                    + (size_t)(3 * MAXB) * 4                // cursors
                    + (size_t)(NE + NN + NU + 3) * 4;       // rowStart CSR arrays
    if (ws_size < required) {
        long total = 2 * nnC;
        fill_debug<<<(total + 255) / 256, 256, 0, stream>>>(out, total, (float)(ws_size >> 20));
        return;
    }

    char* w = (char*)d_ws;
    float* entA     = (float*)w; w += (size_t)neC * 4;
    float* nodeU_A  = (float*)w; w += (size_t)nuC * 4;
    float* nodeU_B  = (float*)w; w += (size_t)nuC * 4;
    float* entNorm  = (float*)w; w += (size_t)NE * 4;
    int* stageEnt   = (int*)w;   w += (size_t)E * 4;
    int* stageNode  = (int*)w;   w += (size_t)E2 * 4;
    int* stageU     = (int*)w;   w += (size_t)NNZ * 4;
    float* stageUv  = (float*)w; w += (size_t)NNZ * 4;
    int* binEnt     = (int*)w;   w += (size_t)E * 4;
    int* binNode    = (int*)w;   w += (size_t)E2 * 4;
    int* binU       = (int*)w;   w += (size_t)NNZ * 4;
    float* binUv    = (float*)w; w += (size_t)NNZ * 4;
    int* cntC       = (int*)w;   w += (size_t)(3 * MAXB) * 4;
    int* startE     = (int*)w;   w += (size_t)(MAXB + 1) * 4;
    int* startN     = (int*)w;   w += (size_t)(MAXB + 1) * 4;
    int* startU     = (int*)w;   w += (size_t)(MAXB + 1) * 4;
    int* curE       = (int*)w;   w += (size_t)MAXB * 4;
    int* curN       = (int*)w;   w += (size_t)MAXB * 4;
    int* curU       = (int*)w;   w += (size_t)MAXB * 4;
    int* rowSE      = (int*)w;   w += (size_t)(NE + 1) * 4;
    int* rowSN      = (int*)w;   w += (size_t)(NN + 1) * 4;
    int* rowSU      = (int*)w;   w += (size_t)(NU + 1) * 4;

    const int* head = eidx;  const int* tail = eidx + E;
    const int* eh   = xidx;  const int* et   = xidx + E2;

    hipMemsetAsync(cntC, 0, (size_t)(3 * MAXB) * 4, stream);

    long initN4 = (nuC > neC ? nuC : neC) / 4;
    init_kernel<<<(initN4 + 255) / 256, 256, 0, stream>>>(
        (const float4*)user_emb, (const float4*)ent_emb,
        (float4*)outUserRes, (float4*)outNodeRes, nuC / 4, neC / 4);

    // ---- build: hist -> scan -> coarse bin -> per-row subsort (CSR) ----
    hist_coarse<<<256, 256, 0, stream>>>(head,  E,   cntC,            BcE);
    hist_coarse<<<256, 256, 0, stream>>>(eh,    E2,  cntC + MAXB,     BcN);
    hist_coarse<<<256, 256, 0, stream>>>(imRow, NNZ, cntC + 2 * MAXB, BcU);

    scan_small<<<1, 256, 0, stream>>>(cntC,            startE, curE, BcE);
    scan_small<<<1, 256, 0, stream>>>(cntC + MAXB,     startN, curN, BcN);
    scan_small<<<1, 256, 0, stream>>>(cntC + 2 * MAXB, startU, curU, BcU);

    bin_pairs<<<(E  + CHUNK - 1) / CHUNK, 256, 0, stream>>>(head, tail, etype, -1, E,  curE, stageEnt);
    bin_pairs<<<(E2 + CHUNK - 1) / CHUNK, 256, 0, stream>>>(eh,   et,   xtype,  0, E2, curN, stageNode);
    bin_user <<<(NNZ + CHUNK - 1) / CHUNK, 256, 0, stream>>>(imRow, imCol, imVal, NNZ, curU, stageU, stageUv);

    subsort<<<BcE, 256, 0, stream>>>(startE, stageEnt,  nullptr, binEnt,  nullptr, rowSE, BcE, NE, E);
    subsort<<<BcN, 256, 0, stream>>>(startN, stageNode, nullptr, binNode, nullptr, rowSN, BcN, NN, E2);
    subsort<<<BcU, 256, 0, stream>>>(startU, stageU,    stageUv, binU,    binUv,   rowSU, BcU, NU, NNZ);

    // ---- 3 hops (compact layout, 4-deep predicated gathers) ----
    const float* entCurP  = ent_emb;   float* entNewP  = entOut;
    const float* nodeOldP = user_emb;  float* nodeNewP = nodeU_A;

    for (int hop = 0; hop < 3; ++hop) {
        ent_gather<<<(NE + 3) / 4, 256, 0, stream>>>(
            entCurP, (const float4*)weight, rowSE, binEnt, entNewP, entNorm, NE);
        node_gather<<<(NN + 3) / 4, 256, 0, stream>>>(
            nodeOldP, entCurP, (const float4*)extraW, rowSN, binNode,
            nodeNewP, outNodeRes, NN, NU);
        user_gather<<<(NU + 3) / 4, 256, 0, stream>>>(
            entNewP, entNorm, rowSU, binU, binUv, outUserRes, NU);

        if (hop == 0) {
            entCurP = entOut;  entNewP = entA;
            nodeOldP = nodeU_A; nodeNewP = nodeU_B;
        } else if (hop == 1) {
            entCurP = entA;    entNewP = entOut;
            nodeOldP = nodeU_B; nodeNewP = nodeU_A;
        }
    }
}

// Round 5
// 969.537 us; speedup vs baseline: 1.1876x; 1.0608x over previous
//
#include <hip/hip_runtime.h>
#include <hip/hip_fp16.h>

#define CDIM 64
#define COARSE_SHIFT 10          // 1024 rows per coarse bucket
#define CHUNK 8192
#define MAXB 256                 // >= max coarse buckets (200000>>10 = 196)

// ---- fp16 pack/unpack (hop-state tables are fp16; accumulation stays fp32) ----
__device__ __forceinline__ float4 h4f(ushort4 h) {
    return make_float4(__half2float(__ushort_as_half(h.x)),
                       __half2float(__ushort_as_half(h.y)),
                       __half2float(__ushort_as_half(h.z)),
                       __half2float(__ushort_as_half(h.w)));
}
__device__ __forceinline__ ushort4 f4h(float4 v) {
    ushort4 h;
    h.x = __half_as_ushort(__float2half_rn(v.x));
    h.y = __half_as_ushort(__float2half_rn(v.y));
    h.z = __half_as_ushort(__float2half_rn(v.z));
    h.w = __half_as_ushort(__float2half_rn(v.w));
    return h;
}

// ---------------- init: residual slots of d_out + fp16 hop-state seed ----------------
__global__ void init_kernel(const float4* __restrict__ user_emb,
                            const float4* __restrict__ ent_emb,
                            float4* __restrict__ outUserRes,
                            float4* __restrict__ outNodeRes,
                            ushort4* __restrict__ uH,
                            ushort4* __restrict__ entH,
                            long nuC4, long neC4) {
    long i = (long)blockIdx.x * blockDim.x + threadIdx.x;
    if (i < nuC4) {
        float4 v = user_emb[i];
        outUserRes[i] = v; outNodeRes[i] = v; uH[i] = f4h(v);
    }
    if (i < neC4) {
        float4 v = ent_emb[i];
        outNodeRes[nuC4 + i] = v; entH[i] = f4h(v);
    }
}

// ---------------- coarse histogram (LDS-staged) ----------------
__global__ void hist_coarse(const int* __restrict__ dst, int n,
                            int* __restrict__ cnt, int Bc) {
    __shared__ int h[MAXB];
    for (int i = threadIdx.x; i < MAXB; i += blockDim.x) h[i] = 0;
    __syncthreads();
    int stride = gridDim.x * blockDim.x;
    for (int e = blockIdx.x * blockDim.x + threadIdx.x; e < n; e += stride)
        atomicAdd(&h[dst[e] >> COARSE_SHIFT], 1);
    __syncthreads();
    for (int b = threadIdx.x; b < Bc; b += blockDim.x)
        if (h[b]) atomicAdd(&cnt[b], h[b]);
}

// ---------------- small exclusive scan (single WG, n<=256) ----------------
__global__ void scan_small(const int* __restrict__ cnt, int* __restrict__ start,
                           int* __restrict__ cursor, int n) {
    __shared__ int tmp[256];
    int x = threadIdx.x;
    int v = (x < n) ? cnt[x] : 0;
    tmp[x] = v; __syncthreads();
    for (int off = 1; off < 256; off <<= 1) {
        int t = (x >= off) ? tmp[x - off] : 0;
        __syncthreads();
        tmp[x] += t;
        __syncthreads();
    }
    if (x < n) { start[x] = tmp[x] - v; cursor[x] = tmp[x] - v; }
    if (x == n - 1) start[n] = tmp[x];
}

// ---------------- coarse binning, LDS-staged segment writes ----------------
// key = rowlocal<<22 | typ<<18 | src   (rowlocal<1024, typ<16, src<2^18)
__global__ void bin_pairs(const int* __restrict__ dst, const int* __restrict__ src,
                          const int* __restrict__ typ, int typeBias, int n,
                          int* __restrict__ cursor, int* __restrict__ stage) {
    __shared__ int h[MAXB];
    __shared__ int base[MAXB];
    int cs = blockIdx.x * CHUNK;
    int ce = min(cs + CHUNK, n);
    for (int i = threadIdx.x; i < MAXB; i += blockDim.x) h[i] = 0;
    __syncthreads();
    for (int e = cs + threadIdx.x; e < ce; e += blockDim.x)
        atomicAdd(&h[dst[e] >> COARSE_SHIFT], 1);
    __syncthreads();
    for (int b = threadIdx.x; b < MAXB; b += blockDim.x) {
        int c = h[b];
        base[b] = c ? atomicAdd(&cursor[b], c) : 0;
        h[b] = 0;
    }
    __syncthreads();
    for (int e = cs + threadIdx.x; e < ce; e += blockDim.x) {
        int d = dst[e];
        int b = d >> COARSE_SHIFT;
        int off = atomicAdd(&h[b], 1);
        stage[base[b] + off] = ((d & 1023) << 22) | ((typ[e] + typeBias) << 18) | src[e];
    }
}

// user variant: key = rowlocal<<22 | col (col<2^22), parallel val array
__global__ void bin_user(const int* __restrict__ row, const int* __restrict__ col,
                         const float* __restrict__ val, int n,
                         int* __restrict__ cursor,
                         int* __restrict__ stage, float* __restrict__ stageVal) {
    __shared__ int h[MAXB];
    __shared__ int base[MAXB];
    int cs = blockIdx.x * CHUNK;
    int ce = min(cs + CHUNK, n);
    for (int i = threadIdx.x; i < MAXB; i += blockDim.x) h[i] = 0;
    __syncthreads();
    for (int e = cs + threadIdx.x; e < ce; e += blockDim.x)
        atomicAdd(&h[row[e] >> COARSE_SHIFT], 1);
    __syncthreads();
    for (int b = threadIdx.x; b < MAXB; b += blockDim.x) {
        int c = h[b];
        base[b] = c ? atomicAdd(&cursor[b], c) : 0;
        h[b] = 0;
    }
    __syncthreads();
    for (int e = cs + threadIdx.x; e < ce; e += blockDim.x) {
        int d = row[e];
        int b = d >> COARSE_SHIFT;
        int off = atomicAdd(&h[b], 1);
        int pos = base[b] + off;
        stage[pos] = ((d & 1023) << 22) | col[e];
        stageVal[pos] = val[e];
    }
}

// ---------------- full per-row sort within coarse bucket (L2-resident) ----------------
__global__ void __launch_bounds__(256)
subsort(const int* __restrict__ coarseStart,
        const int* __restrict__ stage, const float* __restrict__ stageVal,
        int* __restrict__ bin, float* __restrict__ binVal,
        int* __restrict__ rowStart, int Bc, int N, int total) {
    __shared__ int h[1024];
    __shared__ int base[1024];
    __shared__ int sarr[256];
    int c = blockIdx.x;
    int s = coarseStart[c], e = coarseStart[c + 1];
    for (int i = threadIdx.x; i < 1024; i += 256) h[i] = 0;
    __syncthreads();
    for (int j = s + threadIdx.x; j < e; j += 256)
        atomicAdd(&h[(stage[j] >> 22) & 1023], 1);
    __syncthreads();
    int t = threadIdx.x;
    int l0 = h[4*t], l1 = h[4*t+1], l2 = h[4*t+2], l3 = h[4*t+3];
    int lsum = l0 + l1 + l2 + l3;
    sarr[t] = lsum;
    __syncthreads();
    for (int off = 1; off < 256; off <<= 1) {
        int v = (t >= off) ? sarr[t - off] : 0;
        __syncthreads();
        sarr[t] += v;
        __syncthreads();
    }
    int excl = sarr[t] - lsum;
    base[4*t] = excl; base[4*t+1] = excl + l0;
    base[4*t+2] = excl + l0 + l1; base[4*t+3] = excl + l0 + l1 + l2;
    __syncthreads();
    int rowBase = c << COARSE_SHIFT;
    for (int i = threadIdx.x; i < 1024; i += 256) {
        int gr = rowBase + i;
        if (gr < N) rowStart[gr] = s + base[i];
    }
    if (threadIdx.x == 0 && c == Bc - 1) rowStart[N] = total;
    for (int i = threadIdx.x; i < 1024; i += 256) h[i] = 0;
    __syncthreads();
    for (int j = s + threadIdx.x; j < e; j += 256) {
        int k = stage[j];
        int r = (k >> 22) & 1023;
        int pos = s + base[r] + atomicAdd(&h[r], 1);
        bin[pos] = k;
        if (binVal) binVal[pos] = stageVal[j];
    }
}

// ---------------- gathers (fp16 sources, fp32 accumulate) ----------------
// One wave per dest row. lane = 16*q + l: q = edge slot base, l = float4 group.
// fp16 row = 128B; per lane 8B (ushort4). Keys coalesced-prefetched + __shfl.
// CORRECTNESS INVARIANT: every __shfl executes in wave-uniform control flow.

__device__ __forceinline__ void fma4(float4& acc, const float4 v, const float4 w) {
    acc.x += v.x * w.x; acc.y += v.y * w.y;
    acc.z += v.z * w.z; acc.w += v.w * w.w;
}

__global__ void __launch_bounds__(256)
ent_gather(const ushort* __restrict__ entCur,
           const float4* __restrict__ weight,
           const int* __restrict__ rowStart,
           const int* __restrict__ bin,
           ushort* __restrict__ entNewH,
           float* __restrict__ entOutF,          // non-null on final hop
           float* __restrict__ entNorm,
           int NE) {
    __shared__ float4 wlds[15 * 16];
    for (int i = threadIdx.x; i < 15 * 16; i += blockDim.x) wlds[i] = weight[i];
    __syncthreads();
    int row = blockIdx.x * (blockDim.x >> 6) + (threadIdx.x >> 6);
    int lane = threadIdx.x & 63;
    int q = lane >> 4, l = lane & 15;
    if (row >= NE) return;
    int start = rowStart[row], end = rowStart[row + 1];
    int deg = end - start;
    int myk = (lane < deg) ? bin[start + lane] : 0;
    int cap = deg < 64 ? deg : 64;
    int full = cap >> 4;
    float4 acc = make_float4(0.f, 0.f, 0.f, 0.f);
    for (int t = 0; t < full; ++t) {
        int e0 = (t << 4) + q;
        int k0 = __shfl(myk, e0,      64);
        int k1 = __shfl(myk, e0 + 4,  64);
        int k2 = __shfl(myk, e0 + 8,  64);
        int k3 = __shfl(myk, e0 + 12, 64);
        ushort4 h0 = ((const ushort4*)(entCur + (long)(k0 & 0x3FFFF) * CDIM))[l];
        ushort4 h1 = ((const ushort4*)(entCur + (long)(k1 & 0x3FFFF) * CDIM))[l];
        ushort4 h2 = ((const ushort4*)(entCur + (long)(k2 & 0x3FFFF) * CDIM))[l];
        ushort4 h3 = ((const ushort4*)(entCur + (long)(k3 & 0x3FFFF) * CDIM))[l];
        fma4(acc, h4f(h0), wlds[((k0 >> 18) & 15) * 16 + l]);
        fma4(acc, h4f(h1), wlds[((k1 >> 18) & 15) * 16 + l]);
        fma4(acc, h4f(h2), wlds[((k2 >> 18) & 15) * 16 + l]);
        fma4(acc, h4f(h3), wlds[((k3 >> 18) & 15) * 16 + l]);
    }
    if (cap & 15) {
        int e0 = (full << 4) + q;
        int k0 = __shfl(myk, e0,      64);
        int k1 = __shfl(myk, e0 + 4,  64);
        int k2 = __shfl(myk, e0 + 8,  64);
        int k3 = __shfl(myk, e0 + 12, 64);
        if (e0 < cap) {
            ushort4 h = ((const ushort4*)(entCur + (long)(k0 & 0x3FFFF) * CDIM))[l];
            fma4(acc, h4f(h), wlds[((k0 >> 18) & 15) * 16 + l]);
        }
        if (e0 + 4 < cap) {
            ushort4 h = ((const ushort4*)(entCur + (long)(k1 & 0x3FFFF) * CDIM))[l];
            fma4(acc, h4f(h), wlds[((k1 >> 18) & 15) * 16 + l]);
        }
        if (e0 + 8 < cap) {
            ushort4 h = ((const ushort4*)(entCur + (long)(k2 & 0x3FFFF) * CDIM))[l];
            fma4(acc, h4f(h), wlds[((k2 >> 18) & 15) * 16 + l]);
        }
        if (e0 + 12 < cap) {
            ushort4 h = ((const ushort4*)(entCur + (long)(k3 & 0x3FFFF) * CDIM))[l];
            fma4(acc, h4f(h), wlds[((k3 >> 18) & 15) * 16 + l]);
        }
    }
    for (int j = start + 64 + q; j < end; j += 4) {
        int k = bin[j];
        ushort4 h = ((const ushort4*)(entCur + (long)(k & 0x3FFFF) * CDIM))[l];
        fma4(acc, h4f(h), wlds[((k >> 18) & 15) * 16 + l]);
    }
    #pragma unroll
    for (int off = 16; off < 64; off <<= 1) {
        acc.x += __shfl_xor(acc.x, off, 64);
        acc.y += __shfl_xor(acc.y, off, 64);
        acc.z += __shfl_xor(acc.z, off, 64);
        acc.w += __shfl_xor(acc.w, off, 64);
    }
    float inv = 1.0f / fmaxf((float)deg, 1.0f);
    float4 mean = make_float4(acc.x * inv, acc.y * inv, acc.z * inv, acc.w * inv);
    float q2 = mean.x * mean.x + mean.y * mean.y + mean.z * mean.z + mean.w * mean.w;
    #pragma unroll
    for (int off = 1; off < 16; off <<= 1) q2 += __shfl_xor(q2, off, 64);
    float n = fmaxf(sqrtf(q2), 1e-12f);
    float rn = 1.0f / n;
    if (q == 0) {
        float4 o = make_float4(mean.x * rn, mean.y * rn, mean.z * rn, mean.w * rn);
        ((ushort4*)(entNewH + (long)row * CDIM))[l] = f4h(o);
        if (entOutF) ((float4*)(entOutF + (long)row * CDIM))[l] = o;
        if (l == 0) entNorm[row] = n;
    }
}

__global__ void __launch_bounds__(256)
node_gather(const ushort* __restrict__ uOld,
            const ushort* __restrict__ entCur,
            const float4* __restrict__ extraW,
            const int* __restrict__ rowStart,
            const int* __restrict__ bin,
            ushort* __restrict__ uNewH,          // null on final hop
            float* __restrict__ resOut,
            int NN, int NU) {
    __shared__ float4 wlds[16 * 16];
    for (int i = threadIdx.x; i < 16 * 16; i += blockDim.x) wlds[i] = extraW[i];
    __syncthreads();
    int row = blockIdx.x * (blockDim.x >> 6) + (threadIdx.x >> 6);
    int lane = threadIdx.x & 63;
    int q = lane >> 4, l = lane & 15;
    if (row >= NN) return;
    int start = rowStart[row], end = rowStart[row + 1];
    int deg = end - start;
    int myk = (lane < deg) ? bin[start + lane] : 0;
    float4* resRow = (float4*)(resOut + (long)row * CDIM);
    float4 rv = make_float4(0.f, 0.f, 0.f, 0.f);
    if (q == 0) rv = resRow[l];                   // hoisted: overlaps gather loop
    int cap = deg < 64 ? deg : 64;
    int full = cap >> 4;
    float4 acc = make_float4(0.f, 0.f, 0.f, 0.f);
    for (int t = 0; t < full; ++t) {
        int e0 = (t << 4) + q;
        int k0 = __shfl(myk, e0,      64);
        int k1 = __shfl(myk, e0 + 4,  64);
        int k2 = __shfl(myk, e0 + 8,  64);
        int k3 = __shfl(myk, e0 + 12, 64);
        int s0 = k0 & 0x3FFFF, s1 = k1 & 0x3FFFF;
        int s2 = k2 & 0x3FFFF, s3 = k3 & 0x3FFFF;
        const ushort* b0 = (s0 < NU) ? uOld + (long)s0 * CDIM : entCur + (long)(s0 - NU) * CDIM;
        const ushort* b1 = (s1 < NU) ? uOld + (long)s1 * CDIM : entCur + (long)(s1 - NU) * CDIM;
        const ushort* b2 = (s2 < NU) ? uOld + (long)s2 * CDIM : entCur + (long)(s2 - NU) * CDIM;
        const ushort* b3 = (s3 < NU) ? uOld + (long)s3 * CDIM : entCur + (long)(s3 - NU) * CDIM;
        ushort4 h0 = ((const ushort4*)b0)[l];
        ushort4 h1 = ((const ushort4*)b1)[l];
        ushort4 h2 = ((const ushort4*)b2)[l];
        ushort4 h3 = ((const ushort4*)b3)[l];
        fma4(acc, h4f(h0), wlds[((k0 >> 18) & 15) * 16 + l]);
        fma4(acc, h4f(h1), wlds[((k1 >> 18) & 15) * 16 + l]);
        fma4(acc, h4f(h2), wlds[((k2 >> 18) & 15) * 16 + l]);
        fma4(acc, h4f(h3), wlds[((k3 >> 18) & 15) * 16 + l]);
    }
    if (cap & 15) {
        int e0 = (full << 4) + q;
        int k0 = __shfl(myk, e0,      64);
        int k1 = __shfl(myk, e0 + 4,  64);
        int k2 = __shfl(myk, e0 + 8,  64);
        int k3 = __shfl(myk, e0 + 12, 64);
        if (e0 < cap) {
            int s = k0 & 0x3FFFF;
            const ushort* b = (s < NU) ? uOld + (long)s * CDIM : entCur + (long)(s - NU) * CDIM;
            fma4(acc, h4f(((const ushort4*)b)[l]), wlds[((k0 >> 18) & 15) * 16 + l]);
        }
        if (e0 + 4 < cap) {
            int s = k1 & 0x3FFFF;
            const ushort* b = (s < NU) ? uOld + (long)s * CDIM : entCur + (long)(s - NU) * CDIM;
            fma4(acc, h4f(((const ushort4*)b)[l]), wlds[((k1 >> 18) & 15) * 16 + l]);
        }
        if (e0 + 8 < cap) {
            int s = k2 & 0x3FFFF;
            const ushort* b = (s < NU) ? uOld + (long)s * CDIM : entCur + (long)(s - NU) * CDIM;
            fma4(acc, h4f(((const ushort4*)b)[l]), wlds[((k2 >> 18) & 15) * 16 + l]);
        }
        if (e0 + 12 < cap) {
            int s = k3 & 0x3FFFF;
            const ushort* b = (s < NU) ? uOld + (long)s * CDIM : entCur + (long)(s - NU) * CDIM;
            fma4(acc, h4f(((const ushort4*)b)[l]), wlds[((k3 >> 18) & 15) * 16 + l]);
        }
    }
    for (int j = start + 64 + q; j < end; j += 4) {
        int k = bin[j];
        int s = k & 0x3FFFF;
        const ushort* b = (s < NU) ? uOld + (long)s * CDIM : entCur + (long)(s - NU) * CDIM;
        fma4(acc, h4f(((const ushort4*)b)[l]), wlds[((k >> 18) & 15) * 16 + l]);
    }
    #pragma unroll
    for (int off = 16; off < 64; off <<= 1) {
        acc.x += __shfl_xor(acc.x, off, 64);
        acc.y += __shfl_xor(acc.y, off, 64);
        acc.z += __shfl_xor(acc.z, off, 64);
        acc.w += __shfl_xor(acc.w, off, 64);
    }
    float inv = 1.0f / fmaxf((float)deg, 1.0f);
    float4 mean = make_float4(acc.x * inv, acc.y * inv, acc.z * inv, acc.w * inv);
    float q2 = mean.x * mean.x + mean.y * mean.y + mean.z * mean.z + mean.w * mean.w;
    #pragma unroll
    for (int off = 1; off < 16; off <<= 1) q2 += __shfl_xor(q2, off, 64);
    float rn = 1.0f / fmaxf(sqrtf(q2), 1e-12f);
    if (q == 0) {
        float4 o = make_float4(mean.x * rn, mean.y * rn, mean.z * rn, mean.w * rn);
        resRow[l] = make_float4(rv.x + o.x, rv.y + o.y, rv.z + o.z, rv.w + o.w);
        if (row < NU && uNewH) ((ushort4*)(uNewH + (long)row * CDIM))[l] = f4h(o);
    }
}

__global__ void __launch_bounds__(256)
user_gather(const ushort* __restrict__ entNewH,
            const float* __restrict__ entNorm,
            const int* __restrict__ rowStart,
            const int* __restrict__ bin,
            const float* __restrict__ binVal,
            float* __restrict__ userRes,
            int NU) {
    int row = blockIdx.x * (blockDim.x >> 6) + (threadIdx.x >> 6);
    int lane = threadIdx.x & 63;
    int q = lane >> 4, l = lane & 15;
    if (row >= NU) return;
    int start = rowStart[row], end = rowStart[row + 1];
    int deg = end - start;
    int myk = 0; float myv = 0.f;
    if (lane < deg) { myk = bin[start + lane]; myv = binVal[start + lane]; }
    float4* resRow = (float4*)(userRes + (long)row * CDIM);
    float4 rv = make_float4(0.f, 0.f, 0.f, 0.f);
    if (q == 0) rv = resRow[l];
    int cap = deg < 64 ? deg : 64;
    int full = cap >> 4;
    float4 acc = make_float4(0.f, 0.f, 0.f, 0.f);
    for (int t = 0; t < full; ++t) {
        int e0 = (t << 4) + q;
        int k0 = __shfl(myk, e0,      64);
        int k1 = __shfl(myk, e0 + 4,  64);
        int k2 = __shfl(myk, e0 + 8,  64);
        int k3 = __shfl(myk, e0 + 12, 64);
        float a0 = __shfl(myv, e0,      64);
        float a1 = __shfl(myv, e0 + 4,  64);
        float a2 = __shfl(myv, e0 + 8,  64);
        float a3 = __shfl(myv, e0 + 12, 64);
        int c0 = k0 & 0x3FFFFF, c1 = k1 & 0x3FFFFF;
        int c2 = k2 & 0x3FFFFF, c3 = k3 & 0x3FFFFF;
        float f0 = entNorm[c0] * a0;
        float f1 = entNorm[c1] * a1;
        float f2 = entNorm[c2] * a2;
        float f3 = entNorm[c3] * a3;
        float4 v0 = h4f(((const ushort4*)(entNewH + (long)c0 * CDIM))[l]);
        float4 v1 = h4f(((const ushort4*)(entNewH + (long)c1 * CDIM))[l]);
        float4 v2 = h4f(((const ushort4*)(entNewH + (long)c2 * CDIM))[l]);
        float4 v3 = h4f(((const ushort4*)(entNewH + (long)c3 * CDIM))[l]);
        acc.x += v0.x * f0; acc.y += v0.y * f0; acc.z += v0.z * f0; acc.w += v0.w * f0;
        acc.x += v1.x * f1; acc.y += v1.y * f1; acc.z += v1.z * f1; acc.w += v1.w * f1;
        acc.x += v2.x * f2; acc.y += v2.y * f2; acc.z += v2.z * f2; acc.w += v2.w * f2;
        acc.x += v3.x * f3; acc.y += v3.y * f3; acc.z += v3.z * f3; acc.w += v3.w * f3;
    }
    if (cap & 15) {
        int e0 = (full << 4) + q;
        int k0 = __shfl(myk, e0,      64);
        int k1 = __shfl(myk, e0 + 4,  64);
        int k2 = __shfl(myk, e0 + 8,  64);
        int k3 = __shfl(myk, e0 + 12, 64);
        float a0 = __shfl(myv, e0,      64);
        float a1 = __shfl(myv, e0 + 4,  64);
        float a2 = __shfl(myv, e0 + 8,  64);
        float a3 = __shfl(myv, e0 + 12, 64);
        if (e0 < cap) {
            int c = k0 & 0x3FFFFF; float f = entNorm[c] * a0;
            float4 v = h4f(((const ushort4*)(entNewH + (long)c * CDIM))[l]);
            acc.x += v.x * f; acc.y += v.y * f; acc.z += v.z * f; acc.w += v.w * f;
        }
        if (e0 + 4 < cap) {
            int c = k1 & 0x3FFFFF; float f = entNorm[c] * a1;
            float4 v = h4f(((const ushort4*)(entNewH + (long)c * CDIM))[l]);
            acc.x += v.x * f; acc.y += v.y * f; acc.z += v.z * f; acc.w += v.w * f;
        }
        if (e0 + 8 < cap) {
            int c = k2 & 0x3FFFFF; float f = entNorm[c] * a2;
            float4 v = h4f(((const ushort4*)(entNewH + (long)c * CDIM))[l]);
            acc.x += v.x * f; acc.y += v.y * f; acc.z += v.z * f; acc.w += v.w * f;
        }
        if (e0 + 12 < cap) {
            int c = k3 & 0x3FFFFF; float f = entNorm[c] * a3;
            float4 v = h4f(((const ushort4*)(entNewH + (long)c * CDIM))[l]);
            acc.x += v.x * f; acc.y += v.y * f; acc.z += v.z * f; acc.w += v.w * f;
        }
    }
    for (int j = start + 64 + q; j < end; j += 4) {
        int col = bin[j] & 0x3FFFFF;
        float f = entNorm[col] * binVal[j];
        float4 v = h4f(((const ushort4*)(entNewH + (long)col * CDIM))[l]);
        acc.x += v.x * f; acc.y += v.y * f;
        acc.z += v.z * f; acc.w += v.w * f;
    }
    #pragma unroll
    for (int off = 16; off < 64; off <<= 1) {
        acc.x += __shfl_xor(acc.x, off, 64);
        acc.y += __shfl_xor(acc.y, off, 64);
        acc.z += __shfl_xor(acc.z, off, 64);
        acc.w += __shfl_xor(acc.w, off, 64);
    }
    float q2 = acc.x * acc.x + acc.y * acc.y + acc.z * acc.z + acc.w * acc.w;
    #pragma unroll
    for (int off = 1; off < 16; off <<= 1) q2 += __shfl_xor(q2, off, 64);
    float rn = 1.0f / fmaxf(sqrtf(q2), 1e-12f);
    if (q == 0) {
        resRow[l] = make_float4(rv.x + acc.x * rn, rv.y + acc.y * rn,
                                rv.z + acc.z * rn, rv.w + acc.w * rn);
    }
}

__global__ void fill_debug(float* __restrict__ out, long n, float val) {
    long i = (long)blockIdx.x * blockDim.x + threadIdx.x;
    if (i < n) out[i] = val;
}

extern "C" void kernel_launch(void* const* d_in, const int* in_sizes, int n_in,
                              void* d_out, int out_size, void* d_ws, size_t ws_size,
                              hipStream_t stream) {
    const float* user_emb = (const float*)d_in[0];
    const float* ent_emb  = (const float*)d_in[1];
    const float* weight   = (const float*)d_in[2];
    const float* extraW   = (const float*)d_in[3];
    const float* imVal    = (const float*)d_in[4];
    const int*   eidx     = (const int*)d_in[5];
    const int*   etype    = (const int*)d_in[6];
    const int*   xidx     = (const int*)d_in[7];
    const int*   xtype    = (const int*)d_in[8];
    const int*   imRow    = (const int*)d_in[9];
    const int*   imCol    = (const int*)d_in[10];

    const int NU  = in_sizes[0] / CDIM;
    const int NE  = in_sizes[1] / CDIM;
    const int NN  = NU + NE;
    const int E   = in_sizes[5] / 2;
    const int E2  = in_sizes[7] / 2;
    const int NNZ = in_sizes[4];
    const long nuC = (long)NU * CDIM, neC = (long)NE * CDIM, nnC = (long)NN * CDIM;

    const int BcE = (NE + 1023) >> 10, BcN = (NN + 1023) >> 10, BcU = (NU + 1023) >> 10;

    float* out = (float*)d_out;
    float* outUserRes = out;            // [0 : nuC]
    float* entOut     = out + nuC;      // [nuC : nnC] final-hop entity (fp32)
    float* outNodeRes = out + nnC;      // [nnC : 2nnC]

    // ---- workspace layout ----
    size_t commonBytes = (size_t)NE * 4                    // entNorm
                       + (size_t)(E + E2 + NNZ) * 4 * 2    // stage + bin keys
                       + (size_t)NNZ * 4 * 2               // stageVal + binVal
                       + (size_t)(3 * MAXB) * 4            // coarse counts
                       + (size_t)(3 * (MAXB + 1)) * 4      // coarse starts
                       + (size_t)(3 * MAXB) * 4            // cursors
                       + (size_t)(NE + NN + NU + 3) * 4;   // rowStart CSR arrays
    size_t halfBytes = ((size_t)neC + nuC) * 2 * 2;        // 2x (entH + uH) fp16
    size_t required = commonBytes + 256 + halfBytes;
    if (ws_size < required) {
        long total = 2 * nnC;
        fill_debug<<<(total + 255) / 256, 256, 0, stream>>>(out, total, (float)(ws_size >> 20));
        return;
    }

    char* w = (char*)d_ws;
    float* entNorm  = (float*)w; w += (size_t)NE * 4;
    int* stageEnt   = (int*)w;   w += (size_t)E * 4;
    int* stageNode  = (int*)w;   w += (size_t)E2 * 4;
    int* stageU     = (int*)w;   w += (size_t)NNZ * 4;
    float* stageUv  = (float*)w; w += (size_t)NNZ * 4;
    int* binEnt     = (int*)w;   w += (size_t)E * 4;
    int* binNode    = (int*)w;   w += (size_t)E2 * 4;
    int* binU       = (int*)w;   w += (size_t)NNZ * 4;
    float* binUv    = (float*)w; w += (size_t)NNZ * 4;
    int* cntC       = (int*)w;   w += (size_t)(3 * MAXB) * 4;
    int* startE     = (int*)w;   w += (size_t)(MAXB + 1) * 4;
    int* startN     = (int*)w;   w += (size_t)(MAXB + 1) * 4;
    int* startU     = (int*)w;   w += (size_t)(MAXB + 1) * 4;
    int* curE       = (int*)w;   w += (size_t)MAXB * 4;
    int* curN       = (int*)w;   w += (size_t)MAXB * 4;
    int* curU       = (int*)w;   w += (size_t)MAXB * 4;
    int* rowSE      = (int*)w;   w += (size_t)(NE + 1) * 4;
    int* rowSN      = (int*)w;   w += (size_t)(NN + 1) * 4;
    int* rowSU      = (int*)w;   w += (size_t)(NU + 1) * 4;
    w = (char*)(((uintptr_t)w + 255) & ~(uintptr_t)255);   // align fp16 tables
    ushort* entH_A  = (ushort*)w; w += (size_t)neC * 2;
    ushort* entH_B  = (ushort*)w; w += (size_t)neC * 2;
    ushort* uH_A    = (ushort*)w; w += (size_t)nuC * 2;
    ushort* uH_B    = (ushort*)w; w += (size_t)nuC * 2;

    const int* head = eidx;  const int* tail = eidx + E;
    const int* eh   = xidx;  const int* et   = xidx + E2;

    hipMemsetAsync(cntC, 0, (size_t)(3 * MAXB) * 4, stream);

    long initN4 = (nuC > neC ? nuC : neC) / 4;
    init_kernel<<<(initN4 + 255) / 256, 256, 0, stream>>>(
        (const float4*)user_emb, (const float4*)ent_emb,
        (float4*)outUserRes, (float4*)outNodeRes,
        (ushort4*)uH_A, (ushort4*)entH_A, nuC / 4, neC / 4);

    // ---- build: hist -> scan -> coarse bin -> per-row subsort (CSR) ----
    hist_coarse<<<256, 256, 0, stream>>>(head,  E,   cntC,            BcE);
    hist_coarse<<<256, 256, 0, stream>>>(eh,    E2,  cntC + MAXB,     BcN);
    hist_coarse<<<256, 256, 0, stream>>>(imRow, NNZ, cntC + 2 * MAXB, BcU);

    scan_small<<<1, 256, 0, stream>>>(cntC,            startE, curE, BcE);
    scan_small<<<1, 256, 0, stream>>>(cntC + MAXB,     startN, curN, BcN);
    scan_small<<<1, 256, 0, stream>>>(cntC + 2 * MAXB, startU, curU, BcU);

    bin_pairs<<<(E  + CHUNK - 1) / CHUNK, 256, 0, stream>>>(head, tail, etype, -1, E,  curE, stageEnt);
    bin_pairs<<<(E2 + CHUNK - 1) / CHUNK, 256, 0, stream>>>(eh,   et,   xtype,  0, E2, curN, stageNode);
    bin_user <<<(NNZ + CHUNK - 1) / CHUNK, 256, 0, stream>>>(imRow, imCol, imVal, NNZ, curU, stageU, stageUv);

    subsort<<<BcE, 256, 0, stream>>>(startE, stageEnt,  nullptr, binEnt,  nullptr, rowSE, BcE, NE, E);
    subsort<<<BcN, 256, 0, stream>>>(startN, stageNode, nullptr, binNode, nullptr, rowSN, BcN, NN, E2);
    subsort<<<BcU, 256, 0, stream>>>(startU, stageU,    stageUv, binU,    binUv,   rowSU, BcU, NU, NNZ);

    // ---- 3 hops (fp16 hop-state, fp32 accumulate/residuals) ----
    const ushort* entCurH = entH_A;  ushort* entNextH = entH_B;
    const ushort* uCurH   = uH_A;    ushort* uNextH   = uH_B;

    for (int hop = 0; hop < 3; ++hop) {
        ent_gather<<<(NE + 3) / 4, 256, 0, stream>>>(
            entCurH, (const float4*)weight, rowSE, binEnt,
            entNextH, (hop == 2) ? entOut : nullptr, entNorm, NE);
        node_gather<<<(NN + 3) / 4, 256, 0, stream>>>(
            uCurH, entCurH, (const float4*)extraW, rowSN, binNode,
            (hop == 2) ? nullptr : uNextH, outNodeRes, NN, NU);
        user_gather<<<(NU + 3) / 4, 256, 0, stream>>>(
            entNextH, entNorm, rowSU, binU, binUv, outUserRes, NU);

        const ushort* te = entCurH; entCurH = entNextH; entNextH = (ushort*)te;
        const ushort* tu = uCurH;   uCurH   = uNextH;   uNextH   = (ushort*)tu;
    }
}

// Round 6
// 958.514 us; speedup vs baseline: 1.2012x; 1.0115x over previous
//
#include <hip/hip_runtime.h>
#include <hip/hip_fp16.h>

#define CDIM 64
#define COARSE_SHIFT 10          // 1024 rows per coarse bucket
#define CHUNK 8192
#define MAXB 256                 // >= max coarse buckets (200000>>10 = 196)

// ---- fp16 pack/unpack (hop-state tables are fp16; accumulation stays fp32) ----
__device__ __forceinline__ float4 h4f(ushort4 h) {
    return make_float4(__half2float(__ushort_as_half(h.x)),
                       __half2float(__ushort_as_half(h.y)),
                       __half2float(__ushort_as_half(h.z)),
                       __half2float(__ushort_as_half(h.w)));
}
__device__ __forceinline__ ushort4 f4h(float4 v) {
    ushort4 h;
    h.x = __half_as_ushort(__float2half_rn(v.x));
    h.y = __half_as_ushort(__float2half_rn(v.y));
    h.z = __half_as_ushort(__float2half_rn(v.z));
    h.w = __half_as_ushort(__float2half_rn(v.w));
    return h;
}
// fmaf form so LLVM's mad-mix can fuse cvt+fma into v_fma_mix_f32
__device__ __forceinline__ void fmah(float4& acc, const ushort4 h, const float4 w) {
    acc.x = fmaf(__half2float(__ushort_as_half(h.x)), w.x, acc.x);
    acc.y = fmaf(__half2float(__ushort_as_half(h.y)), w.y, acc.y);
    acc.z = fmaf(__half2float(__ushort_as_half(h.z)), w.z, acc.z);
    acc.w = fmaf(__half2float(__ushort_as_half(h.w)), w.w, acc.w);
}

// ---------------- init: residual slots of d_out + fp16 hop-state seed ----------------
// uH/entH point into ONE contiguous allH_A buffer (user rows first, then entity).
__global__ void init_kernel(const float4* __restrict__ user_emb,
                            const float4* __restrict__ ent_emb,
                            float4* __restrict__ outUserRes,
                            float4* __restrict__ outNodeRes,
                            ushort4* __restrict__ uH,
                            ushort4* __restrict__ entH,
                            long nuC4, long neC4) {
    long i = (long)blockIdx.x * blockDim.x + threadIdx.x;
    if (i < nuC4) {
        float4 v = user_emb[i];
        outUserRes[i] = v; outNodeRes[i] = v; uH[i] = f4h(v);
    }
    if (i < neC4) {
        float4 v = ent_emb[i];
        outNodeRes[nuC4 + i] = v; entH[i] = f4h(v);
    }
}

// ---------------- coarse histogram (LDS-staged) ----------------
__global__ void hist_coarse(const int* __restrict__ dst, int n,
                            int* __restrict__ cnt, int Bc) {
    __shared__ int h[MAXB];
    for (int i = threadIdx.x; i < MAXB; i += blockDim.x) h[i] = 0;
    __syncthreads();
    int stride = gridDim.x * blockDim.x;
    for (int e = blockIdx.x * blockDim.x + threadIdx.x; e < n; e += stride)
        atomicAdd(&h[dst[e] >> COARSE_SHIFT], 1);
    __syncthreads();
    for (int b = threadIdx.x; b < Bc; b += blockDim.x)
        if (h[b]) atomicAdd(&cnt[b], h[b]);
}

// ---------------- small exclusive scan (single WG, n<=256) ----------------
__global__ void scan_small(const int* __restrict__ cnt, int* __restrict__ start,
                           int* __restrict__ cursor, int n) {
    __shared__ int tmp[256];
    int x = threadIdx.x;
    int v = (x < n) ? cnt[x] : 0;
    tmp[x] = v; __syncthreads();
    for (int off = 1; off < 256; off <<= 1) {
        int t = (x >= off) ? tmp[x - off] : 0;
        __syncthreads();
        tmp[x] += t;
        __syncthreads();
    }
    if (x < n) { start[x] = tmp[x] - v; cursor[x] = tmp[x] - v; }
    if (x == n - 1) start[n] = tmp[x];
}

// ---------------- coarse binning, LDS-staged segment writes ----------------
// key = rowlocal<<22 | typ<<18 | src   (rowlocal<1024, typ<16, src<2^18)
__global__ void bin_pairs(const int* __restrict__ dst, const int* __restrict__ src,
                          const int* __restrict__ typ, int typeBias, int n,
                          int* __restrict__ cursor, int* __restrict__ stage) {
    __shared__ int h[MAXB];
    __shared__ int base[MAXB];
    int cs = blockIdx.x * CHUNK;
    int ce = min(cs + CHUNK, n);
    for (int i = threadIdx.x; i < MAXB; i += blockDim.x) h[i] = 0;
    __syncthreads();
    for (int e = cs + threadIdx.x; e < ce; e += blockDim.x)
        atomicAdd(&h[dst[e] >> COARSE_SHIFT], 1);
    __syncthreads();
    for (int b = threadIdx.x; b < MAXB; b += blockDim.x) {
        int c = h[b];
        base[b] = c ? atomicAdd(&cursor[b], c) : 0;
        h[b] = 0;
    }
    __syncthreads();
    for (int e = cs + threadIdx.x; e < ce; e += blockDim.x) {
        int d = dst[e];
        int b = d >> COARSE_SHIFT;
        int off = atomicAdd(&h[b], 1);
        stage[base[b] + off] = ((d & 1023) << 22) | ((typ[e] + typeBias) << 18) | src[e];
    }
}

// user variant: key = rowlocal<<22 | col (col<2^22), parallel val array
__global__ void bin_user(const int* __restrict__ row, const int* __restrict__ col,
                         const float* __restrict__ val, int n,
                         int* __restrict__ cursor,
                         int* __restrict__ stage, float* __restrict__ stageVal) {
    __shared__ int h[MAXB];
    __shared__ int base[MAXB];
    int cs = blockIdx.x * CHUNK;
    int ce = min(cs + CHUNK, n);
    for (int i = threadIdx.x; i < MAXB; i += blockDim.x) h[i] = 0;
    __syncthreads();
    for (int e = cs + threadIdx.x; e < ce; e += blockDim.x)
        atomicAdd(&h[row[e] >> COARSE_SHIFT], 1);
    __syncthreads();
    for (int b = threadIdx.x; b < MAXB; b += blockDim.x) {
        int c = h[b];
        base[b] = c ? atomicAdd(&cursor[b], c) : 0;
        h[b] = 0;
    }
    __syncthreads();
    for (int e = cs + threadIdx.x; e < ce; e += blockDim.x) {
        int d = row[e];
        int b = d >> COARSE_SHIFT;
        int off = atomicAdd(&h[b], 1);
        int pos = base[b] + off;
        stage[pos] = ((d & 1023) << 22) | col[e];
        stageVal[pos] = val[e];
    }
}

// ---------------- full per-row sort within coarse bucket (L2-resident) ----------------
__global__ void __launch_bounds__(256)
subsort(const int* __restrict__ coarseStart,
        const int* __restrict__ stage, const float* __restrict__ stageVal,
        int* __restrict__ bin, float* __restrict__ binVal,
        int* __restrict__ rowStart, int Bc, int N, int total) {
    __shared__ int h[1024];
    __shared__ int base[1024];
    __shared__ int sarr[256];
    int c = blockIdx.x;
    int s = coarseStart[c], e = coarseStart[c + 1];
    for (int i = threadIdx.x; i < 1024; i += 256) h[i] = 0;
    __syncthreads();
    for (int j = s + threadIdx.x; j < e; j += 256)
        atomicAdd(&h[(stage[j] >> 22) & 1023], 1);
    __syncthreads();
    int t = threadIdx.x;
    int l0 = h[4*t], l1 = h[4*t+1], l2 = h[4*t+2], l3 = h[4*t+3];
    int lsum = l0 + l1 + l2 + l3;
    sarr[t] = lsum;
    __syncthreads();
    for (int off = 1; off < 256; off <<= 1) {
        int v = (t >= off) ? sarr[t - off] : 0;
        __syncthreads();
        sarr[t] += v;
        __syncthreads();
    }
    int excl = sarr[t] - lsum;
    base[4*t] = excl; base[4*t+1] = excl + l0;
    base[4*t+2] = excl + l0 + l1; base[4*t+3] = excl + l0 + l1 + l2;
    __syncthreads();
    int rowBase = c << COARSE_SHIFT;
    for (int i = threadIdx.x; i < 1024; i += 256) {
        int gr = rowBase + i;
        if (gr < N) rowStart[gr] = s + base[i];
    }
    if (threadIdx.x == 0 && c == Bc - 1) rowStart[N] = total;
    for (int i = threadIdx.x; i < 1024; i += 256) h[i] = 0;
    __syncthreads();
    for (int j = s + threadIdx.x; j < e; j += 256) {
        int k = stage[j];
        int r = (k >> 22) & 1023;
        int pos = s + base[r] + atomicAdd(&h[r], 1);
        bin[pos] = k;
        if (binVal) binVal[pos] = stageVal[j];
    }
}

// ---------------- gathers (fp16 sources, fp32 accumulate) ----------------
// One wave per dest row. lane = 16*q + l: q = edge slot base, l = float4 group.
// Keys coalesced-prefetched + __shfl in wave-uniform control flow (all 64 lanes
// active at every shfl; lanes >= deg hold myk = 0, a valid row).

__global__ void __launch_bounds__(256)
ent_gather(const ushort* __restrict__ entCur,
           const float4* __restrict__ weight,
           const int* __restrict__ rowStart,
           const int* __restrict__ bin,
           ushort* __restrict__ entNewH,
           float* __restrict__ entOutF,          // non-null on final hop
           float* __restrict__ entNorm,
           int NE) {
    __shared__ float4 wlds[15 * 16];
    for (int i = threadIdx.x; i < 15 * 16; i += blockDim.x) wlds[i] = weight[i];
    __syncthreads();
    int row = blockIdx.x * (blockDim.x >> 6) + (threadIdx.x >> 6);
    int lane = threadIdx.x & 63;
    int q = lane >> 4, l = lane & 15;
    if (row >= NE) return;
    int start = rowStart[row], end = rowStart[row + 1];
    int deg = end - start;
    int myk = (lane < deg) ? bin[start + lane] : 0;
    int cap = deg < 64 ? deg : 64;
    int full = cap >> 4;
    float4 acc = make_float4(0.f, 0.f, 0.f, 0.f);
    for (int t = 0; t < full; ++t) {
        int e0 = (t << 4) + q;
        int k0 = __shfl(myk, e0,      64);
        int k1 = __shfl(myk, e0 + 4,  64);
        int k2 = __shfl(myk, e0 + 8,  64);
        int k3 = __shfl(myk, e0 + 12, 64);
        ushort4 h0 = ((const ushort4*)(entCur + (long)(k0 & 0x3FFFF) * CDIM))[l];
        ushort4 h1 = ((const ushort4*)(entCur + (long)(k1 & 0x3FFFF) * CDIM))[l];
        ushort4 h2 = ((const ushort4*)(entCur + (long)(k2 & 0x3FFFF) * CDIM))[l];
        ushort4 h3 = ((const ushort4*)(entCur + (long)(k3 & 0x3FFFF) * CDIM))[l];
        fmah(acc, h0, wlds[((k0 >> 18) & 15) * 16 + l]);
        fmah(acc, h1, wlds[((k1 >> 18) & 15) * 16 + l]);
        fmah(acc, h2, wlds[((k2 >> 18) & 15) * 16 + l]);
        fmah(acc, h3, wlds[((k3 >> 18) & 15) * 16 + l]);
    }
    if (cap & 15) {
        int e0 = (full << 4) + q;
        int k0 = __shfl(myk, e0,      64);
        int k1 = __shfl(myk, e0 + 4,  64);
        int k2 = __shfl(myk, e0 + 8,  64);
        int k3 = __shfl(myk, e0 + 12, 64);
        if (e0 < cap) {
            ushort4 h = ((const ushort4*)(entCur + (long)(k0 & 0x3FFFF) * CDIM))[l];
            fmah(acc, h, wlds[((k0 >> 18) & 15) * 16 + l]);
        }
        if (e0 + 4 < cap) {
            ushort4 h = ((const ushort4*)(entCur + (long)(k1 & 0x3FFFF) * CDIM))[l];
            fmah(acc, h, wlds[((k1 >> 18) & 15) * 16 + l]);
        }
        if (e0 + 8 < cap) {
            ushort4 h = ((const ushort4*)(entCur + (long)(k2 & 0x3FFFF) * CDIM))[l];
            fmah(acc, h, wlds[((k2 >> 18) & 15) * 16 + l]);
        }
        if (e0 + 12 < cap) {
            ushort4 h = ((const ushort4*)(entCur + (long)(k3 & 0x3FFFF) * CDIM))[l];
            fmah(acc, h, wlds[((k3 >> 18) & 15) * 16 + l]);
        }
    }
    for (int j = start + 64 + q; j < end; j += 4) {
        int k = bin[j];
        ushort4 h = ((const ushort4*)(entCur + (long)(k & 0x3FFFF) * CDIM))[l];
        fmah(acc, h, wlds[((k >> 18) & 15) * 16 + l]);
    }
    #pragma unroll
    for (int off = 16; off < 64; off <<= 1) {
        acc.x += __shfl_xor(acc.x, off, 64);
        acc.y += __shfl_xor(acc.y, off, 64);
        acc.z += __shfl_xor(acc.z, off, 64);
        acc.w += __shfl_xor(acc.w, off, 64);
    }
    float inv = 1.0f / fmaxf((float)deg, 1.0f);
    float4 mean = make_float4(acc.x * inv, acc.y * inv, acc.z * inv, acc.w * inv);
    float q2 = mean.x * mean.x + mean.y * mean.y + mean.z * mean.z + mean.w * mean.w;
    #pragma unroll
    for (int off = 1; off < 16; off <<= 1) q2 += __shfl_xor(q2, off, 64);
    float n = fmaxf(sqrtf(q2), 1e-12f);
    float rn = 1.0f / n;
    if (q == 0) {
        float4 o = make_float4(mean.x * rn, mean.y * rn, mean.z * rn, mean.w * rn);
        ((ushort4*)(entNewH + (long)row * CDIM))[l] = f4h(o);
        if (entOutF) ((float4*)(entOutF + (long)row * CDIM))[l] = o;
        if (l == 0) entNorm[row] = n;
    }
}

// Unified fp16 node table [NN][CDIM] (user rows 0..NU-1, entity rows NU..NN-1):
// single base pointer, NO per-edge table select.
__global__ void __launch_bounds__(256)
node_gather(const ushort* __restrict__ allCur,
            const float4* __restrict__ extraW,
            const int* __restrict__ rowStart,
            const int* __restrict__ bin,
            ushort* __restrict__ uNewH,          // null on final hop
            float* __restrict__ resOut,
            int NN, int NU) {
    __shared__ float4 wlds[16 * 16];
    for (int i = threadIdx.x; i < 16 * 16; i += blockDim.x) wlds[i] = extraW[i];
    __syncthreads();
    int row = blockIdx.x * (blockDim.x >> 6) + (threadIdx.x >> 6);
    int lane = threadIdx.x & 63;
    int q = lane >> 4, l = lane & 15;
    if (row >= NN) return;
    int start = rowStart[row], end = rowStart[row + 1];
    int deg = end - start;
    int myk = (lane < deg) ? bin[start + lane] : 0;
    float4* resRow = (float4*)(resOut + (long)row * CDIM);
    float4 rv = make_float4(0.f, 0.f, 0.f, 0.f);
    if (q == 0) rv = resRow[l];                   // hoisted: overlaps gather loop
    int cap = deg < 64 ? deg : 64;
    int full = cap >> 4;
    float4 acc = make_float4(0.f, 0.f, 0.f, 0.f);
    for (int t = 0; t < full; ++t) {
        int e0 = (t << 4) + q;
        int k0 = __shfl(myk, e0,      64);
        int k1 = __shfl(myk, e0 + 4,  64);
        int k2 = __shfl(myk, e0 + 8,  64);
        int k3 = __shfl(myk, e0 + 12, 64);
        ushort4 h0 = ((const ushort4*)(allCur + (long)(k0 & 0x3FFFF) * CDIM))[l];
        ushort4 h1 = ((const ushort4*)(allCur + (long)(k1 & 0x3FFFF) * CDIM))[l];
        ushort4 h2 = ((const ushort4*)(allCur + (long)(k2 & 0x3FFFF) * CDIM))[l];
        ushort4 h3 = ((const ushort4*)(allCur + (long)(k3 & 0x3FFFF) * CDIM))[l];
        fmah(acc, h0, wlds[((k0 >> 18) & 15) * 16 + l]);
        fmah(acc, h1, wlds[((k1 >> 18) & 15) * 16 + l]);
        fmah(acc, h2, wlds[((k2 >> 18) & 15) * 16 + l]);
        fmah(acc, h3, wlds[((k3 >> 18) & 15) * 16 + l]);
    }
    if (cap & 15) {
        int e0 = (full << 4) + q;
        int k0 = __shfl(myk, e0,      64);
        int k1 = __shfl(myk, e0 + 4,  64);
        int k2 = __shfl(myk, e0 + 8,  64);
        int k3 = __shfl(myk, e0 + 12, 64);
        if (e0 < cap) {
            ushort4 h = ((const ushort4*)(allCur + (long)(k0 & 0x3FFFF) * CDIM))[l];
            fmah(acc, h, wlds[((k0 >> 18) & 15) * 16 + l]);
        }
        if (e0 + 4 < cap) {
            ushort4 h = ((const ushort4*)(allCur + (long)(k1 & 0x3FFFF) * CDIM))[l];
            fmah(acc, h, wlds[((k1 >> 18) & 15) * 16 + l]);
        }
        if (e0 + 8 < cap) {
            ushort4 h = ((const ushort4*)(allCur + (long)(k2 & 0x3FFFF) * CDIM))[l];
            fmah(acc, h, wlds[((k2 >> 18) & 15) * 16 + l]);
        }
        if (e0 + 12 < cap) {
            ushort4 h = ((const ushort4*)(allCur + (long)(k3 & 0x3FFFF) * CDIM))[l];
            fmah(acc, h, wlds[((k3 >> 18) & 15) * 16 + l]);
        }
    }
    for (int j = start + 64 + q; j < end; j += 4) {
        int k = bin[j];
        ushort4 h = ((const ushort4*)(allCur + (long)(k & 0x3FFFF) * CDIM))[l];
        fmah(acc, h, wlds[((k >> 18) & 15) * 16 + l]);
    }
    #pragma unroll
    for (int off = 16; off < 64; off <<= 1) {
        acc.x += __shfl_xor(acc.x, off, 64);
        acc.y += __shfl_xor(acc.y, off, 64);
        acc.z += __shfl_xor(acc.z, off, 64);
        acc.w += __shfl_xor(acc.w, off, 64);
    }
    float inv = 1.0f / fmaxf((float)deg, 1.0f);
    float4 mean = make_float4(acc.x * inv, acc.y * inv, acc.z * inv, acc.w * inv);
    float q2 = mean.x * mean.x + mean.y * mean.y + mean.z * mean.z + mean.w * mean.w;
    #pragma unroll
    for (int off = 1; off < 16; off <<= 1) q2 += __shfl_xor(q2, off, 64);
    float rn = 1.0f / fmaxf(sqrtf(q2), 1e-12f);
    if (q == 0) {
        float4 o = make_float4(mean.x * rn, mean.y * rn, mean.z * rn, mean.w * rn);
        resRow[l] = make_float4(rv.x + o.x, rv.y + o.y, rv.z + o.z, rv.w + o.w);
        if (row < NU && uNewH) ((ushort4*)(uNewH + (long)row * CDIM))[l] = f4h(o);
    }
}

__global__ void __launch_bounds__(256)
user_gather(const ushort* __restrict__ entNewH,
            const float* __restrict__ entNorm,
            const int* __restrict__ rowStart,
            const int* __restrict__ bin,
            const float* __restrict__ binVal,
            float* __restrict__ userRes,
            int NU) {
    int row = blockIdx.x * (blockDim.x >> 6) + (threadIdx.x >> 6);
    int lane = threadIdx.x & 63;
    int q = lane >> 4, l = lane & 15;
    if (row >= NU) return;
    int start = rowStart[row], end = rowStart[row + 1];
    int deg = end - start;
    int myk = 0; float myv = 0.f;
    if (lane < deg) { myk = bin[start + lane]; myv = binVal[start + lane]; }
    float4* resRow = (float4*)(userRes + (long)row * CDIM);
    float4 rv = make_float4(0.f, 0.f, 0.f, 0.f);
    if (q == 0) rv = resRow[l];
    int cap = deg < 64 ? deg : 64;
    int full = cap >> 4;
    float4 acc = make_float4(0.f, 0.f, 0.f, 0.f);
    for (int t = 0; t < full; ++t) {
        int e0 = (t << 4) + q;
        int k0 = __shfl(myk, e0,      64);
        int k1 = __shfl(myk, e0 + 4,  64);
        int k2 = __shfl(myk, e0 + 8,  64);
        int k3 = __shfl(myk, e0 + 12, 64);
        float a0 = __shfl(myv, e0,      64);
        float a1 = __shfl(myv, e0 + 4,  64);
        float a2 = __shfl(myv, e0 + 8,  64);
        float a3 = __shfl(myv, e0 + 12, 64);
        int c0 = k0 & 0x3FFFFF, c1 = k1 & 0x3FFFFF;
        int c2 = k2 & 0x3FFFFF, c3 = k3 & 0x3FFFFF;
        float f0 = entNorm[c0] * a0;
        float f1 = entNorm[c1] * a1;
        float f2 = entNorm[c2] * a2;
        float f3 = entNorm[c3] * a3;
        float4 v0 = h4f(((const ushort4*)(entNewH + (long)c0 * CDIM))[l]);
        float4 v1 = h4f(((const ushort4*)(entNewH + (long)c1 * CDIM))[l]);
        float4 v2 = h4f(((const ushort4*)(entNewH + (long)c2 * CDIM))[l]);
        float4 v3 = h4f(((const ushort4*)(entNewH + (long)c3 * CDIM))[l]);
        acc.x += v0.x * f0; acc.y += v0.y * f0; acc.z += v0.z * f0; acc.w += v0.w * f0;
        acc.x += v1.x * f1; acc.y += v1.y * f1; acc.z += v1.z * f1; acc.w += v1.w * f1;
        acc.x += v2.x * f2; acc.y += v2.y * f2; acc.z += v2.z * f2; acc.w += v2.w * f2;
        acc.x += v3.x * f3; acc.y += v3.y * f3; acc.z += v3.z * f3; acc.w += v3.w * f3;
    }
    if (cap & 15) {
        int e0 = (full << 4) + q;
        int k0 = __shfl(myk, e0,      64);
        int k1 = __shfl(myk, e0 + 4,  64);
        int k2 = __shfl(myk, e0 + 8,  64);
        int k3 = __shfl(myk, e0 + 12, 64);
        float a0 = __shfl(myv, e0,      64);
        float a1 = __shfl(myv, e0 + 4,  64);
        float a2 = __shfl(myv, e0 + 8,  64);
        float a3 = __shfl(myv, e0 + 12, 64);
        if (e0 < cap) {
            int c = k0 & 0x3FFFFF; float f = entNorm[c] * a0;
            float4 v = h4f(((const ushort4*)(entNewH + (long)c * CDIM))[l]);
            acc.x += v.x * f; acc.y += v.y * f; acc.z += v.z * f; acc.w += v.w * f;
        }
        if (e0 + 4 < cap) {
            int c = k1 & 0x3FFFFF; float f = entNorm[c] * a1;
            float4 v = h4f(((const ushort4*)(entNewH + (long)c * CDIM))[l]);
            acc.x += v.x * f; acc.y += v.y * f; acc.z += v.z * f; acc.w += v.w * f;
        }
        if (e0 + 8 < cap) {
            int c = k2 & 0x3FFFFF; float f = entNorm[c] * a2;
            float4 v = h4f(((const ushort4*)(entNewH + (long)c * CDIM))[l]);
            acc.x += v.x * f; acc.y += v.y * f; acc.z += v.z * f; acc.w += v.w * f;
        }
        if (e0 + 12 < cap) {
            int c = k3 & 0x3FFFFF; float f = entNorm[c] * a3;
            float4 v = h4f(((const ushort4*)(entNewH + (long)c * CDIM))[l]);
            acc.x += v.x * f; acc.y += v.y * f; acc.z += v.z * f; acc.w += v.w * f;
        }
    }
    for (int j = start + 64 + q; j < end; j += 4) {
        int col = bin[j] & 0x3FFFFF;
        float f = entNorm[col] * binVal[j];
        float4 v = h4f(((const ushort4*)(entNewH + (long)col * CDIM))[l]);
        acc.x += v.x * f; acc.y += v.y * f;
        acc.z += v.z * f; acc.w += v.w * f;
    }
    #pragma unroll
    for (int off = 16; off < 64; off <<= 1) {
        acc.x += __shfl_xor(acc.x, off, 64);
        acc.y += __shfl_xor(acc.y, off, 64);
        acc.z += __shfl_xor(acc.z, off, 64);
        acc.w += __shfl_xor(acc.w, off, 64);
    }
    float q2 = acc.x * acc.x + acc.y * acc.y + acc.z * acc.z + acc.w * acc.w;
    #pragma unroll
    for (int off = 1; off < 16; off <<= 1) q2 += __shfl_xor(q2, off, 64);
    float rn = 1.0f / fmaxf(sqrtf(q2), 1e-12f);
    if (q == 0) {
        resRow[l] = make_float4(rv.x + acc.x * rn, rv.y + acc.y * rn,
                                rv.z + acc.z * rn, rv.w + acc.w * rn);
    }
}

__global__ void fill_debug(float* __restrict__ out, long n, float val) {
    long i = (long)blockIdx.x * blockDim.x + threadIdx.x;
    if (i < n) out[i] = val;
}

extern "C" void kernel_launch(void* const* d_in, const int* in_sizes, int n_in,
                              void* d_out, int out_size, void* d_ws, size_t ws_size,
                              hipStream_t stream) {
    const float* user_emb = (const float*)d_in[0];
    const float* ent_emb  = (const float*)d_in[1];
    const float* weight   = (const float*)d_in[2];
    const float* extraW   = (const float*)d_in[3];
    const float* imVal    = (const float*)d_in[4];
    const int*   eidx     = (const int*)d_in[5];
    const int*   etype    = (const int*)d_in[6];
    const int*   xidx     = (const int*)d_in[7];
    const int*   xtype    = (const int*)d_in[8];
    const int*   imRow    = (const int*)d_in[9];
    const int*   imCol    = (const int*)d_in[10];

    const int NU  = in_sizes[0] / CDIM;
    const int NE  = in_sizes[1] / CDIM;
    const int NN  = NU + NE;
    const int E   = in_sizes[5] / 2;
    const int E2  = in_sizes[7] / 2;
    const int NNZ = in_sizes[4];
    const long nuC = (long)NU * CDIM, neC = (long)NE * CDIM, nnC = (long)NN * CDIM;

    const int BcE = (NE + 1023) >> 10, BcN = (NN + 1023) >> 10, BcU = (NU + 1023) >> 10;

    float* out = (float*)d_out;
    float* outUserRes = out;            // [0 : nuC]
    float* entOut     = out + nuC;      // [nuC : nnC] final-hop entity (fp32)
    float* outNodeRes = out + nnC;      // [nnC : 2nnC]

    // ---- workspace layout ----
    size_t commonBytes = (size_t)NE * 4                    // entNorm
                       + (size_t)(E + E2 + NNZ) * 4 * 2    // stage + bin keys
                       + (size_t)NNZ * 4 * 2               // stageVal + binVal
                       + (size_t)(3 * MAXB) * 4            // coarse counts
                       + (size_t)(3 * (MAXB + 1)) * 4      // coarse starts
                       + (size_t)(3 * MAXB) * 4            // cursors
                       + (size_t)(NE + NN + NU + 3) * 4;   // rowStart CSR arrays
    size_t halfBytes = (size_t)nnC * 2 * 2;                // 2x unified fp16 node table
    size_t required = commonBytes + 256 + halfBytes;
    if (ws_size < required) {
        long total = 2 * nnC;
        fill_debug<<<(total + 255) / 256, 256, 0, stream>>>(out, total, (float)(ws_size >> 20));
        return;
    }

    char* w = (char*)d_ws;
    float* entNorm  = (float*)w; w += (size_t)NE * 4;
    int* stageEnt   = (int*)w;   w += (size_t)E * 4;
    int* stageNode  = (int*)w;   w += (size_t)E2 * 4;
    int* stageU     = (int*)w;   w += (size_t)NNZ * 4;
    float* stageUv  = (float*)w; w += (size_t)NNZ * 4;
    int* binEnt     = (int*)w;   w += (size_t)E * 4;
    int* binNode    = (int*)w;   w += (size_t)E2 * 4;
    int* binU       = (int*)w;   w += (size_t)NNZ * 4;
    float* binUv    = (float*)w; w += (size_t)NNZ * 4;
    int* cntC       = (int*)w;   w += (size_t)(3 * MAXB) * 4;
    int* startE     = (int*)w;   w += (size_t)(MAXB + 1) * 4;
    int* startN     = (int*)w;   w += (size_t)(MAXB + 1) * 4;
    int* startU     = (int*)w;   w += (size_t)(MAXB + 1) * 4;
    int* curE       = (int*)w;   w += (size_t)MAXB * 4;
    int* curN       = (int*)w;   w += (size_t)MAXB * 4;
    int* curU       = (int*)w;   w += (size_t)MAXB * 4;
    int* rowSE      = (int*)w;   w += (size_t)(NE + 1) * 4;
    int* rowSN      = (int*)w;   w += (size_t)(NN + 1) * 4;
    int* rowSU      = (int*)w;   w += (size_t)(NU + 1) * 4;
    w = (char*)(((uintptr_t)w + 255) & ~(uintptr_t)255);   // align fp16 tables
    ushort* allH_A  = (ushort*)w; w += (size_t)nnC * 2;    // [user | entity] fp16
    ushort* allH_B  = (ushort*)w; w += (size_t)nnC * 2;

    const size_t entOff = (size_t)NU * CDIM;               // entity half offset

    const int* head = eidx;  const int* tail = eidx + E;
    const int* eh   = xidx;  const int* et   = xidx + E2;

    hipMemsetAsync(cntC, 0, (size_t)(3 * MAXB) * 4, stream);

    long initN4 = (nuC > neC ? nuC : neC) / 4;
    init_kernel<<<(initN4 + 255) / 256, 256, 0, stream>>>(
        (const float4*)user_emb, (const float4*)ent_emb,
        (float4*)outUserRes, (float4*)outNodeRes,
        (ushort4*)allH_A, (ushort4*)(allH_A + entOff), nuC / 4, neC / 4);

    // ---- build: hist -> scan -> coarse bin -> per-row subsort (CSR) ----
    hist_coarse<<<256, 256, 0, stream>>>(head,  E,   cntC,            BcE);
    hist_coarse<<<256, 256, 0, stream>>>(eh,    E2,  cntC + MAXB,     BcN);
    hist_coarse<<<256, 256, 0, stream>>>(imRow, NNZ, cntC + 2 * MAXB, BcU);

    scan_small<<<1, 256, 0, stream>>>(cntC,            startE, curE, BcE);
    scan_small<<<1, 256, 0, stream>>>(cntC + MAXB,     startN, curN, BcN);
    scan_small<<<1, 256, 0, stream>>>(cntC + 2 * MAXB, startU, curU, BcU);

    bin_pairs<<<(E  + CHUNK - 1) / CHUNK, 256, 0, stream>>>(head, tail, etype, -1, E,  curE, stageEnt);
    bin_pairs<<<(E2 + CHUNK - 1) / CHUNK, 256, 0, stream>>>(eh,   et,   xtype,  0, E2, curN, stageNode);
    bin_user <<<(NNZ + CHUNK - 1) / CHUNK, 256, 0, stream>>>(imRow, imCol, imVal, NNZ, curU, stageU, stageUv);

    subsort<<<BcE, 256, 0, stream>>>(startE, stageEnt,  nullptr, binEnt,  nullptr, rowSE, BcE, NE, E);
    subsort<<<BcN, 256, 0, stream>>>(startN, stageNode, nullptr, binNode, nullptr, rowSN, BcN, NN, E2);
    subsort<<<BcU, 256, 0, stream>>>(startU, stageU,    stageUv, binU,    binUv,   rowSU, BcU, NU, NNZ);

    // ---- 3 hops (unified fp16 node table, select-free node_gather) ----
    ushort* allCur  = allH_A;
    ushort* allNext = allH_B;

    for (int hop = 0; hop < 3; ++hop) {
        ent_gather<<<(NE + 3) / 4, 256, 0, stream>>>(
            allCur + entOff, (const float4*)weight, rowSE, binEnt,
            allNext + entOff, (hop == 2) ? entOut : nullptr, entNorm, NE);
        node_gather<<<(NN + 3) / 4, 256, 0, stream>>>(
            allCur, (const float4*)extraW, rowSN, binNode,
            (hop == 2) ? nullptr : allNext, outNodeRes, NN, NU);
        user_gather<<<(NU + 3) / 4, 256, 0, stream>>>(
            allNext + entOff, entNorm, rowSU, binU, binUv, outUserRes, NU);

        ushort* t = allCur; allCur = allNext; allNext = t;
    }
}

// Round 8
// 786.874 us; speedup vs baseline: 1.4632x; 1.2181x over previous
//
#include <hip/hip_runtime.h>
#include <hip/hip_fp16.h>

#define CDIM 64
#define COARSE_SHIFT 10          // 1024 rows per coarse bucket
#define CHUNK 8192
#define MAXB 256                 // >= max coarse buckets (200000>>10 = 196)

// ---- fp16 pack/unpack (hop-state tables are fp16; accumulation stays fp32) ----
__device__ __forceinline__ float4 h4f(ushort4 h) {
    return make_float4(__half2float(__ushort_as_half(h.x)),
                       __half2float(__ushort_as_half(h.y)),
                       __half2float(__ushort_as_half(h.z)),
                       __half2float(__ushort_as_half(h.w)));
}
__device__ __forceinline__ ushort4 f4h(float4 v) {
    ushort4 h;
    h.x = __half_as_ushort(__float2half_rn(v.x));
    h.y = __half_as_ushort(__float2half_rn(v.y));
    h.z = __half_as_ushort(__float2half_rn(v.z));
    h.w = __half_as_ushort(__float2half_rn(v.w));
    return h;
}
// fmaf forms so LLVM mad-mix can fuse cvt+fma into v_fma_mix_f32
__device__ __forceinline__ void fmah(float4& acc, const ushort4 h, const float4 w) {
    acc.x = fmaf(__half2float(__ushort_as_half(h.x)), w.x, acc.x);
    acc.y = fmaf(__half2float(__ushort_as_half(h.y)), w.y, acc.y);
    acc.z = fmaf(__half2float(__ushort_as_half(h.z)), w.z, acc.z);
    acc.w = fmaf(__half2float(__ushort_as_half(h.w)), w.w, acc.w);
}
__device__ __forceinline__ void fmahs(float4& acc, const ushort4 h, const float f) {
    acc.x = fmaf(__half2float(__ushort_as_half(h.x)), f, acc.x);
    acc.y = fmaf(__half2float(__ushort_as_half(h.y)), f, acc.y);
    acc.z = fmaf(__half2float(__ushort_as_half(h.z)), f, acc.z);
    acc.w = fmaf(__half2float(__ushort_as_half(h.w)), f, acc.w);
}

// ---------------- init: residual slots of d_out + fp16 hop-state seed ----------------
__global__ void init_kernel(const float4* __restrict__ user_emb,
                            const float4* __restrict__ ent_emb,
                            float4* __restrict__ outUserRes,
                            float4* __restrict__ outNodeRes,
                            ushort4* __restrict__ uH,
                            ushort4* __restrict__ entH,
                            long nuC4, long neC4) {
    long i = (long)blockIdx.x * blockDim.x + threadIdx.x;
    if (i < nuC4) {
        float4 v = user_emb[i];
        outUserRes[i] = v; outNodeRes[i] = v; uH[i] = f4h(v);
    }
    if (i < neC4) {
        float4 v = ent_emb[i];
        outNodeRes[nuC4 + i] = v; entH[i] = f4h(v);
    }
}

// ---------------- coarse histogram (LDS-staged) ----------------
__global__ void hist_coarse(const int* __restrict__ dst, int n,
                            int* __restrict__ cnt, int Bc) {
    __shared__ int h[MAXB];
    for (int i = threadIdx.x; i < MAXB; i += blockDim.x) h[i] = 0;
    __syncthreads();
    int stride = gridDim.x * blockDim.x;
    for (int e = blockIdx.x * blockDim.x + threadIdx.x; e < n; e += stride)
        atomicAdd(&h[dst[e] >> COARSE_SHIFT], 1);
    __syncthreads();
    for (int b = threadIdx.x; b < Bc; b += blockDim.x)
        if (h[b]) atomicAdd(&cnt[b], h[b]);
}

// ---------------- small exclusive scan (single WG, n<=256) ----------------
__global__ void scan_small(const int* __restrict__ cnt, int* __restrict__ start,
                           int* __restrict__ cursor, int n) {
    __shared__ int tmp[256];
    int x = threadIdx.x;
    int v = (x < n) ? cnt[x] : 0;
    tmp[x] = v; __syncthreads();
    for (int off = 1; off < 256; off <<= 1) {
        int t = (x >= off) ? tmp[x - off] : 0;
        __syncthreads();
        tmp[x] += t;
        __syncthreads();
    }
    if (x < n) { start[x] = tmp[x] - v; cursor[x] = tmp[x] - v; }
    if (x == n - 1) start[n] = tmp[x];
}

// ---------------- coarse binning, LDS-staged segment writes ----------------
// key = rowlocal<<22 | typ<<18 | src   (rowlocal<1024, typ<16, src<2^18)
__global__ void bin_pairs(const int* __restrict__ dst, const int* __restrict__ src,
                          const int* __restrict__ typ, int typeBias, int n,
                          int* __restrict__ cursor, int* __restrict__ stage) {
    __shared__ int h[MAXB];
    __shared__ int base[MAXB];
    int cs = blockIdx.x * CHUNK;
    int ce = min(cs + CHUNK, n);
    for (int i = threadIdx.x; i < MAXB; i += blockDim.x) h[i] = 0;
    __syncthreads();
    for (int e = cs + threadIdx.x; e < ce; e += blockDim.x)
        atomicAdd(&h[dst[e] >> COARSE_SHIFT], 1);
    __syncthreads();
    for (int b = threadIdx.x; b < MAXB; b += blockDim.x) {
        int c = h[b];
        base[b] = c ? atomicAdd(&cursor[b], c) : 0;
        h[b] = 0;
    }
    __syncthreads();
    for (int e = cs + threadIdx.x; e < ce; e += blockDim.x) {
        int d = dst[e];
        int b = d >> COARSE_SHIFT;
        int off = atomicAdd(&h[b], 1);
        stage[base[b] + off] = ((d & 1023) << 22) | ((typ[e] + typeBias) << 18) | src[e];
    }
}

// user variant: key = rowlocal<<22 | col (col<2^22), parallel val array
__global__ void bin_user(const int* __restrict__ row, const int* __restrict__ col,
                         const float* __restrict__ val, int n,
                         int* __restrict__ cursor,
                         int* __restrict__ stage, float* __restrict__ stageVal) {
    __shared__ int h[MAXB];
    __shared__ int base[MAXB];
    int cs = blockIdx.x * CHUNK;
    int ce = min(cs + CHUNK, n);
    for (int i = threadIdx.x; i < MAXB; i += blockDim.x) h[i] = 0;
    __syncthreads();
    for (int e = cs + threadIdx.x; e < ce; e += blockDim.x)
        atomicAdd(&h[row[e] >> COARSE_SHIFT], 1);
    __syncthreads();
    for (int b = threadIdx.x; b < MAXB; b += blockDim.x) {
        int c = h[b];
        base[b] = c ? atomicAdd(&cursor[b], c) : 0;
        h[b] = 0;
    }
    __syncthreads();
    for (int e = cs + threadIdx.x; e < ce; e += blockDim.x) {
        int d = row[e];
        int b = d >> COARSE_SHIFT;
        int off = atomicAdd(&h[b], 1);
        int pos = base[b] + off;
        stage[pos] = ((d & 1023) << 22) | col[e];
        stageVal[pos] = val[e];
    }
}

// ---------------- full per-row sort within coarse bucket (L2-resident) ----------------
__global__ void __launch_bounds__(256)
subsort(const int* __restrict__ coarseStart,
        const int* __restrict__ stage, const float* __restrict__ stageVal,
        int* __restrict__ bin, float* __restrict__ binVal,
        int* __restrict__ rowStart, int Bc, int N, int total) {
    __shared__ int h[1024];
    __shared__ int base[1024];
    __shared__ int sarr[256];
    int c = blockIdx.x;
    int s = coarseStart[c], e = coarseStart[c + 1];
    for (int i = threadIdx.x; i < 1024; i += 256) h[i] = 0;
    __syncthreads();
    for (int j = s + threadIdx.x; j < e; j += 256)
        atomicAdd(&h[(stage[j] >> 22) & 1023], 1);
    __syncthreads();
    int t = threadIdx.x;
    int l0 = h[4*t], l1 = h[4*t+1], l2 = h[4*t+2], l3 = h[4*t+3];
    int lsum = l0 + l1 + l2 + l3;
    sarr[t] = lsum;
    __syncthreads();
    for (int off = 1; off < 256; off <<= 1) {
        int v = (t >= off) ? sarr[t - off] : 0;
        __syncthreads();
        sarr[t] += v;
        __syncthreads();
    }
    int excl = sarr[t] - lsum;
    base[4*t] = excl; base[4*t+1] = excl + l0;
    base[4*t+2] = excl + l0 + l1; base[4*t+3] = excl + l0 + l1 + l2;
    __syncthreads();
    int rowBase = c << COARSE_SHIFT;
    for (int i = threadIdx.x; i < 1024; i += 256) {
        int gr = rowBase + i;
        if (gr < N) rowStart[gr] = s + base[i];
    }
    if (threadIdx.x == 0 && c == Bc - 1) rowStart[N] = total;
    for (int i = threadIdx.x; i < 1024; i += 256) h[i] = 0;
    __syncthreads();
    for (int j = s + threadIdx.x; j < e; j += 256) {
        int k = stage[j];
        int r = (k >> 22) & 1023;
        int pos = s + base[r] + atomicAdd(&h[r], 1);
        bin[pos] = k;
        if (binVal) binVal[pos] = stageVal[j];
    }
}

// ---------------- gathers: QUARTER-WAVE rows ----------------
// One row per 16-lane quarter (fp16 row = 128B = 16 x ushort4): each lane owns
// 4 fixed channels -> NO cross-lane reduce for the sum; only the norm reduces
// within the quarter (shfl_xor 1,2,4,8). Keys held 2-deep in registers
// (deg <= 32; overflow loop beyond), broadcast by __shfl from within-quarter
// lanes. CORRECTNESS INVARIANT: every __shfl executes in wave-uniform control
// flow (main-loop trip count = wave-max of per-quarter caps; no early return
// before the reduce). Lanes beyond deg hold key 0 (valid row 0); dead slots
// are neutralized via zero-weight row (ent/node) or f=0 (user).

__global__ void __launch_bounds__(256)
ent_gather(const ushort* __restrict__ entCur,
           const float4* __restrict__ weight,
           const int* __restrict__ rowStart,
           const int* __restrict__ bin,
           ushort* __restrict__ entNewH,
           float* __restrict__ entOutF,          // non-null on final hop
           float* __restrict__ entNorm,
           int NE) {
    __shared__ float4 wlds[16 * 16];              // row 15 = zeros (mask row)
    for (int i = threadIdx.x; i < 15 * 16; i += blockDim.x) wlds[i] = weight[i];
    for (int i = threadIdx.x; i < 16; i += blockDim.x)
        wlds[15 * 16 + i] = make_float4(0.f, 0.f, 0.f, 0.f);
    __syncthreads();
    int lane = threadIdx.x & 63;
    int l = lane & 15;
    int qbase = lane & 48;
    int row = blockIdx.x * 16 + ((threadIdx.x >> 6) << 2) + (lane >> 4);
    bool ok = row < NE;
    int start = 0, deg = 0;
    if (ok) { start = rowStart[row]; deg = rowStart[row + 1] - start; }
    int myk0 = (l < deg)      ? bin[start + l]      : 0;
    int myk1 = (16 + l < deg) ? bin[start + 16 + l] : 0;
    int cap = deg < 32 ? deg : 32;
    int capm = cap;
    capm = max(capm, __shfl_xor(capm, 16, 64));
    capm = max(capm, __shfl_xor(capm, 32, 64));
    int nb = (capm + 3) >> 2;
    float4 acc = make_float4(0.f, 0.f, 0.f, 0.f);
    for (int t = 0; t < nb; ++t) {
        int e0 = t << 2;
        int k0 = __shfl((e0     < 16) ? myk0 : myk1, qbase + ( e0      & 15), 64);
        int k1 = __shfl((e0 + 1 < 16) ? myk0 : myk1, qbase + ((e0 + 1) & 15), 64);
        int k2 = __shfl((e0 + 2 < 16) ? myk0 : myk1, qbase + ((e0 + 2) & 15), 64);
        int k3 = __shfl((e0 + 3 < 16) ? myk0 : myk1, qbase + ((e0 + 3) & 15), 64);
        ushort4 h0 = ((const ushort4*)(entCur + (long)(k0 & 0x3FFFF) * CDIM))[l];
        ushort4 h1 = ((const ushort4*)(entCur + (long)(k1 & 0x3FFFF) * CDIM))[l];
        ushort4 h2 = ((const ushort4*)(entCur + (long)(k2 & 0x3FFFF) * CDIM))[l];
        ushort4 h3 = ((const ushort4*)(entCur + (long)(k3 & 0x3FFFF) * CDIM))[l];
        int r0 = (e0     < cap) ? ((k0 >> 18) & 15) : 15;
        int r1 = (e0 + 1 < cap) ? ((k1 >> 18) & 15) : 15;
        int r2 = (e0 + 2 < cap) ? ((k2 >> 18) & 15) : 15;
        int r3 = (e0 + 3 < cap) ? ((k3 >> 18) & 15) : 15;
        fmah(acc, h0, wlds[r0 * 16 + l]);
        fmah(acc, h1, wlds[r1 * 16 + l]);
        fmah(acc, h2, wlds[r2 * 16 + l]);
        fmah(acc, h3, wlds[r3 * 16 + l]);
    }
    for (int e = 32; e < deg; ++e) {              // rare overflow, per-quarter
        int k = bin[start + e];
        ushort4 h = ((const ushort4*)(entCur + (long)(k & 0x3FFFF) * CDIM))[l];
        fmah(acc, h, wlds[((k >> 18) & 15) * 16 + l]);
    }
    float inv = 1.0f / fmaxf((float)deg, 1.0f);
    float4 mean = make_float4(acc.x * inv, acc.y * inv, acc.z * inv, acc.w * inv);
    float q2 = mean.x * mean.x + mean.y * mean.y + mean.z * mean.z + mean.w * mean.w;
    q2 += __shfl_xor(q2, 1, 64);
    q2 += __shfl_xor(q2, 2, 64);
    q2 += __shfl_xor(q2, 4, 64);
    q2 += __shfl_xor(q2, 8, 64);
    float n = fmaxf(sqrtf(q2), 1e-12f);
    float rn = 1.0f / n;
    if (ok) {
        float4 o = make_float4(mean.x * rn, mean.y * rn, mean.z * rn, mean.w * rn);
        ((ushort4*)(entNewH + (long)row * CDIM))[l] = f4h(o);
        if (entOutF) ((float4*)(entOutF + (long)row * CDIM))[l] = o;
        if (l == 0) entNorm[row] = n;
    }
}

// Unified fp16 node table [NN][CDIM] (user rows first): single base pointer.
__global__ void __launch_bounds__(256)
node_gather(const ushort* __restrict__ allCur,
            const float4* __restrict__ extraW,
            const int* __restrict__ rowStart,
            const int* __restrict__ bin,
            ushort* __restrict__ uNewH,          // null on final hop
            float* __restrict__ resOut,
            int NN, int NU) {
    __shared__ float4 wlds[17 * 16];              // row 16 = zeros (mask row)
    for (int i = threadIdx.x; i < 16 * 16; i += blockDim.x) wlds[i] = extraW[i];
    for (int i = threadIdx.x; i < 16; i += blockDim.x)
        wlds[16 * 16 + i] = make_float4(0.f, 0.f, 0.f, 0.f);
    __syncthreads();
    int lane = threadIdx.x & 63;
    int l = lane & 15;
    int qbase = lane & 48;
    int row = blockIdx.x * 16 + ((threadIdx.x >> 6) << 2) + (lane >> 4);
    bool ok = row < NN;
    int start = 0, deg = 0;
    if (ok) { start = rowStart[row]; deg = rowStart[row + 1] - start; }
    int myk0 = (l < deg)      ? bin[start + l]      : 0;
    int myk1 = (16 + l < deg) ? bin[start + 16 + l] : 0;
    float4* resRow = (float4*)(resOut + (long)row * CDIM);
    float4 rvv = make_float4(0.f, 0.f, 0.f, 0.f);
    if (ok) rvv = resRow[l];                      // hoisted: overlaps gather loop
    int cap = deg < 32 ? deg : 32;
    int capm = cap;
    capm = max(capm, __shfl_xor(capm, 16, 64));
    capm = max(capm, __shfl_xor(capm, 32, 64));
    int nb = (capm + 3) >> 2;
    float4 acc = make_float4(0.f, 0.f, 0.f, 0.f);
    for (int t = 0; t < nb; ++t) {
        int e0 = t << 2;
        int k0 = __shfl((e0     < 16) ? myk0 : myk1, qbase + ( e0      & 15), 64);
        int k1 = __shfl((e0 + 1 < 16) ? myk0 : myk1, qbase + ((e0 + 1) & 15), 64);
        int k2 = __shfl((e0 + 2 < 16) ? myk0 : myk1, qbase + ((e0 + 2) & 15), 64);
        int k3 = __shfl((e0 + 3 < 16) ? myk0 : myk1, qbase + ((e0 + 3) & 15), 64);
        ushort4 h0 = ((const ushort4*)(allCur + (long)(k0 & 0x3FFFF) * CDIM))[l];
        ushort4 h1 = ((const ushort4*)(allCur + (long)(k1 & 0x3FFFF) * CDIM))[l];
        ushort4 h2 = ((const ushort4*)(allCur + (long)(k2 & 0x3FFFF) * CDIM))[l];
        ushort4 h3 = ((const ushort4*)(allCur + (long)(k3 & 0x3FFFF) * CDIM))[l];
        int r0 = (e0     < cap) ? ((k0 >> 18) & 15) : 16;
        int r1 = (e0 + 1 < cap) ? ((k1 >> 18) & 15) : 16;
        int r2 = (e0 + 2 < cap) ? ((k2 >> 18) & 15) : 16;
        int r3 = (e0 + 3 < cap) ? ((k3 >> 18) & 15) : 16;
        fmah(acc, h0, wlds[r0 * 16 + l]);
        fmah(acc, h1, wlds[r1 * 16 + l]);
        fmah(acc, h2, wlds[r2 * 16 + l]);
        fmah(acc, h3, wlds[r3 * 16 + l]);
    }
    for (int e = 32; e < deg; ++e) {
        int k = bin[start + e];
        ushort4 h = ((const ushort4*)(allCur + (long)(k & 0x3FFFF) * CDIM))[l];
        fmah(acc, h, wlds[((k >> 18) & 15) * 16 + l]);
    }
    float inv = 1.0f / fmaxf((float)deg, 1.0f);
    float4 mean = make_float4(acc.x * inv, acc.y * inv, acc.z * inv, acc.w * inv);
    float q2 = mean.x * mean.x + mean.y * mean.y + mean.z * mean.z + mean.w * mean.w;
    q2 += __shfl_xor(q2, 1, 64);
    q2 += __shfl_xor(q2, 2, 64);
    q2 += __shfl_xor(q2, 4, 64);
    q2 += __shfl_xor(q2, 8, 64);
    float rn = 1.0f / fmaxf(sqrtf(q2), 1e-12f);
    if (ok) {
        float4 o = make_float4(mean.x * rn, mean.y * rn, mean.z * rn, mean.w * rn);
        resRow[l] = make_float4(rvv.x + o.x, rvv.y + o.y, rvv.z + o.z, rvv.w + o.w);
        if (row < NU && uNewH) ((ushort4*)(uNewH + (long)row * CDIM))[l] = f4h(o);
    }
}

__global__ void __launch_bounds__(256)
user_gather(const ushort* __restrict__ entNewH,
            const float* __restrict__ entNorm,
            const int* __restrict__ rowStart,
            const int* __restrict__ bin,
            const float* __restrict__ binVal,
            float* __restrict__ userRes,
            int NU) {
    int lane = threadIdx.x & 63;
    int l = lane & 15;
    int qbase = lane & 48;
    int row = blockIdx.x * 16 + ((threadIdx.x >> 6) << 2) + (lane >> 4);
    bool ok = row < NU;
    int start = 0, deg = 0;
    if (ok) { start = rowStart[row]; deg = rowStart[row + 1] - start; }
    int myk0 = 0, myk1 = 0; float myv0 = 0.f, myv1 = 0.f;
    if (l < deg)      { myk0 = bin[start + l];      myv0 = binVal[start + l]; }
    if (16 + l < deg) { myk1 = bin[start + 16 + l]; myv1 = binVal[start + 16 + l]; }
    float4* resRow = (float4*)(userRes + (long)row * CDIM);
    float4 rvv = make_float4(0.f, 0.f, 0.f, 0.f);
    if (ok) rvv = resRow[l];
    int cap = deg < 32 ? deg : 32;
    int capm = cap;
    capm = max(capm, __shfl_xor(capm, 16, 64));
    capm = max(capm, __shfl_xor(capm, 32, 64));
    int nb = (capm + 3) >> 2;
    float4 acc = make_float4(0.f, 0.f, 0.f, 0.f);
    for (int t = 0; t < nb; ++t) {
        int e0 = t << 2;
        int k0 = __shfl((e0     < 16) ? myk0 : myk1, qbase + ( e0      & 15), 64);
        int k1 = __shfl((e0 + 1 < 16) ? myk0 : myk1, qbase + ((e0 + 1) & 15), 64);
        int k2 = __shfl((e0 + 2 < 16) ? myk0 : myk1, qbase + ((e0 + 2) & 15), 64);
        int k3 = __shfl((e0 + 3 < 16) ? myk0 : myk1, qbase + ((e0 + 3) & 15), 64);
        float a0 = __shfl((e0     < 16) ? myv0 : myv1, qbase + ( e0      & 15), 64);
        float a1 = __shfl((e0 + 1 < 16) ? myv0 : myv1, qbase + ((e0 + 1) & 15), 64);
        float a2 = __shfl((e0 + 2 < 16) ? myv0 : myv1, qbase + ((e0 + 2) & 15), 64);
        float a3 = __shfl((e0 + 3 < 16) ? myv0 : myv1, qbase + ((e0 + 3) & 15), 64);
        int c0 = k0 & 0x3FFFFF, c1 = k1 & 0x3FFFFF;
        int c2 = k2 & 0x3FFFFF, c3 = k3 & 0x3FFFFF;
        float f0 = (e0     < cap) ? entNorm[c0] * a0 : 0.f;
        float f1 = (e0 + 1 < cap) ? entNorm[c1] * a1 : 0.f;
        float f2 = (e0 + 2 < cap) ? entNorm[c2] * a2 : 0.f;
        float f3 = (e0 + 3 < cap) ? entNorm[c3] * a3 : 0.f;
        ushort4 h0 = ((const ushort4*)(entNewH + (long)c0 * CDIM))[l];
        ushort4 h1 = ((const ushort4*)(entNewH + (long)c1 * CDIM))[l];
        ushort4 h2 = ((const ushort4*)(entNewH + (long)c2 * CDIM))[l];
        ushort4 h3 = ((const ushort4*)(entNewH + (long)c3 * CDIM))[l];
        fmahs(acc, h0, f0);
        fmahs(acc, h1, f1);
        fmahs(acc, h2, f2);
        fmahs(acc, h3, f3);
    }
    for (int e = 32; e < deg; ++e) {
        int k = bin[start + e];
        float a = binVal[start + e];
        int c = k & 0x3FFFFF;
        float f = entNorm[c] * a;
        ushort4 h = ((const ushort4*)(entNewH + (long)c * CDIM))[l];
        fmahs(acc, h, f);
    }
    float q2 = acc.x * acc.x + acc.y * acc.y + acc.z * acc.z + acc.w * acc.w;
    q2 += __shfl_xor(q2, 1, 64);
    q2 += __shfl_xor(q2, 2, 64);
    q2 += __shfl_xor(q2, 4, 64);
    q2 += __shfl_xor(q2, 8, 64);
    float rn = 1.0f / fmaxf(sqrtf(q2), 1e-12f);
    if (ok) {
        resRow[l] = make_float4(rvv.x + acc.x * rn, rvv.y + acc.y * rn,
                                rvv.z + acc.z * rn, rvv.w + acc.w * rn);
    }
}

__global__ void fill_debug(float* __restrict__ out, long n, float val) {
    long i = (long)blockIdx.x * blockDim.x + threadIdx.x;
    if (i < n) out[i] = val;
}

extern "C" void kernel_launch(void* const* d_in, const int* in_sizes, int n_in,
                              void* d_out, int out_size, void* d_ws, size_t ws_size,
                              hipStream_t stream) {
    const float* user_emb = (const float*)d_in[0];
    const float* ent_emb  = (const float*)d_in[1];
    const float* weight   = (const float*)d_in[2];
    const float* extraW   = (const float*)d_in[3];
    const float* imVal    = (const float*)d_in[4];
    const int*   eidx     = (const int*)d_in[5];
    const int*   etype    = (const int*)d_in[6];
    const int*   xidx     = (const int*)d_in[7];
    const int*   xtype    = (const int*)d_in[8];
    const int*   imRow    = (const int*)d_in[9];
    const int*   imCol    = (const int*)d_in[10];

    const int NU  = in_sizes[0] / CDIM;
    const int NE  = in_sizes[1] / CDIM;
    const int NN  = NU + NE;
    const int E   = in_sizes[5] / 2;
    const int E2  = in_sizes[7] / 2;
    const int NNZ = in_sizes[4];
    const long nuC = (long)NU * CDIM, neC = (long)NE * CDIM, nnC = (long)NN * CDIM;

    const int BcE = (NE + 1023) >> 10, BcN = (NN + 1023) >> 10, BcU = (NU + 1023) >> 10;

    float* out = (float*)d_out;
    float* outUserRes = out;            // [0 : nuC]
    float* entOut     = out + nuC;      // [nuC : nnC] final-hop entity (fp32)
    float* outNodeRes = out + nnC;      // [nnC : 2nnC]

    // ---- workspace layout ----
    size_t commonBytes = (size_t)NE * 4                    // entNorm
                       + (size_t)(E + E2 + NNZ) * 4 * 2    // stage + bin keys
                       + (size_t)NNZ * 4 * 2               // stageVal + binVal
                       + (size_t)(3 * MAXB) * 4            // coarse counts
                       + (size_t)(3 * (MAXB + 1)) * 4      // coarse starts
                       + (size_t)(3 * MAXB) * 4            // cursors
                       + (size_t)(NE + NN + NU + 3) * 4;   // rowStart CSR arrays
    size_t halfBytes = (size_t)nnC * 2 * 2;                // 2x unified fp16 node table
    size_t required = commonBytes + 256 + halfBytes;
    if (ws_size < required) {
        long total = 2 * nnC;
        fill_debug<<<(total + 255) / 256, 256, 0, stream>>>(out, total, (float)(ws_size >> 20));
        return;
    }

    char* w = (char*)d_ws;
    float* entNorm  = (float*)w; w += (size_t)NE * 4;
    int* stageEnt   = (int*)w;   w += (size_t)E * 4;
    int* stageNode  = (int*)w;   w += (size_t)E2 * 4;
    int* stageU     = (int*)w;   w += (size_t)NNZ * 4;
    float* stageUv  = (float*)w; w += (size_t)NNZ * 4;
    int* binEnt     = (int*)w;   w += (size_t)E * 4;
    int* binNode    = (int*)w;   w += (size_t)E2 * 4;
    int* binU       = (int*)w;   w += (size_t)NNZ * 4;
    float* binUv    = (float*)w; w += (size_t)NNZ * 4;
    int* cntC       = (int*)w;   w += (size_t)(3 * MAXB) * 4;
    int* startE     = (int*)w;   w += (size_t)(MAXB + 1) * 4;
    int* startN     = (int*)w;   w += (size_t)(MAXB + 1) * 4;
    int* startU     = (int*)w;   w += (size_t)(MAXB + 1) * 4;
    int* curE       = (int*)w;   w += (size_t)MAXB * 4;
    int* curN       = (int*)w;   w += (size_t)MAXB * 4;
    int* curU       = (int*)w;   w += (size_t)MAXB * 4;
    int* rowSE      = (int*)w;   w += (size_t)(NE + 1) * 4;
    int* rowSN      = (int*)w;   w += (size_t)(NN + 1) * 4;
    int* rowSU      = (int*)w;   w += (size_t)(NU + 1) * 4;
    w = (char*)(((uintptr_t)w + 255) & ~(uintptr_t)255);   // align fp16 tables
    ushort* allH_A  = (ushort*)w; w += (size_t)nnC * 2;    // [user | entity] fp16
    ushort* allH_B  = (ushort*)w; w += (size_t)nnC * 2;

    const size_t entOff = (size_t)NU * CDIM;               // entity half offset

    const int* head = eidx;  const int* tail = eidx + E;
    const int* eh   = xidx;  const int* et   = xidx + E2;

    hipMemsetAsync(cntC, 0, (size_t)(3 * MAXB) * 4, stream);

    long initN4 = (nuC > neC ? nuC : neC) / 4;
    init_kernel<<<(initN4 + 255) / 256, 256, 0, stream>>>(
        (const float4*)user_emb, (const float4*)ent_emb,
        (float4*)outUserRes, (float4*)outNodeRes,
        (ushort4*)allH_A, (ushort4*)(allH_A + entOff), nuC / 4, neC / 4);

    // ---- build: hist -> scan -> coarse bin -> per-row subsort (CSR) ----
    hist_coarse<<<256, 256, 0, stream>>>(head,  E,   cntC,            BcE);
    hist_coarse<<<256, 256, 0, stream>>>(eh,    E2,  cntC + MAXB,     BcN);
    hist_coarse<<<256, 256, 0, stream>>>(imRow, NNZ, cntC + 2 * MAXB, BcU);

    scan_small<<<1, 256, 0, stream>>>(cntC,            startE, curE, BcE);
    scan_small<<<1, 256, 0, stream>>>(cntC + MAXB,     startN, curN, BcN);
    scan_small<<<1, 256, 0, stream>>>(cntC + 2 * MAXB, startU, curU, BcU);

    bin_pairs<<<(E  + CHUNK - 1) / CHUNK, 256, 0, stream>>>(head, tail, etype, -1, E,  curE, stageEnt);
    bin_pairs<<<(E2 + CHUNK - 1) / CHUNK, 256, 0, stream>>>(eh,   et,   xtype,  0, E2, curN, stageNode);
    bin_user <<<(NNZ + CHUNK - 1) / CHUNK, 256, 0, stream>>>(imRow, imCol, imVal, NNZ, curU, stageU, stageUv);

    subsort<<<BcE, 256, 0, stream>>>(startE, stageEnt,  nullptr, binEnt,  nullptr, rowSE, BcE, NE, E);
    subsort<<<BcN, 256, 0, stream>>>(startN, stageNode, nullptr, binNode, nullptr, rowSN, BcN, NN, E2);
    subsort<<<BcU, 256, 0, stream>>>(startU, stageU,    stageUv, binU,    binUv,   rowSU, BcU, NU, NNZ);

    // ---- 3 hops (unified fp16 node table, quarter-wave gathers) ----
    ushort* allCur  = allH_A;
    ushort* allNext = allH_B;

    for (int hop = 0; hop < 3; ++hop) {
        ent_gather<<<(NE + 15) / 16, 256, 0, stream>>>(
            allCur + entOff, (const float4*)weight, rowSE, binEnt,
            allNext + entOff, (hop == 2) ? entOut : nullptr, entNorm, NE);
        node_gather<<<(NN + 15) / 16, 256, 0, stream>>>(
            allCur, (const float4*)extraW, rowSN, binNode,
            (hop == 2) ? nullptr : allNext, outNodeRes, NN, NU);
        user_gather<<<(NU + 15) / 16, 256, 0, stream>>>(
            allNext + entOff, entNorm, rowSU, binU, binUv, outUserRes, NU);

        ushort* t = allCur; allCur = allNext; allNext = t;
    }
}